// Round 4
// baseline (3524.066 us; speedup 1.0000x reference)
//
#include <hip/hip_runtime.h>

// PDA_GNN: 3-branch LightGCN with bucketed dst-partition + LDS-accumulate convs,
// fused normalize/concat/MLP/softmax tail. N=100000, E=1250000, D=64.

constexpr int NN = 100000;
constexpr int NE = 1250000;
constexpr int BROWS = 128;                       // dst nodes per bucket
constexpr int NB = (NN + BROWS - 1) / BROWS;     // 782 buckets
constexpr int CHUNK = 8192;                      // edges per partition block
constexpr int NCHUNK = (NE + CHUNK - 1) / CHUNK; // 153

// ---------------------------------------------------------------------------
// In-degree count for all 3 edge sets in one launch (needed for dinv + buckets)
// ---------------------------------------------------------------------------
__global__ __launch_bounds__(256) void k_cnt3(const int* __restrict__ e0, const int* __restrict__ e1,
                                              const int* __restrict__ e2, int* __restrict__ cnt) {
    int i = blockIdx.x * 256 + threadIdx.x;
    if (i < NE) atomicAdd(&cnt[e0[NE + i]], 1);
    else if (i < 2 * NE) atomicAdd(&cnt[NN + e1[NE + i - NE]], 1);
    else if (i < 3 * NE) atomicAdd(&cnt[2 * NN + e2[NE + i - 2 * NE]], 1);
}

__global__ __launch_bounds__(256) void k_dinv(const int* __restrict__ cnt, float* __restrict__ dinv) {
    int i = blockIdx.x * 256 + threadIdx.x;
    if (i < 3 * NN) {
        int c = cnt[i];
        dinv[i] = (c > 0) ? (1.0f / sqrtf((float)c)) : 0.0f;
    }
}

// ---------------------------------------------------------------------------
// Bucket counts (sum of per-node counts) + exclusive scan -> bstart, gcur.
// One workgroup; wave 0 does the scans.
// ---------------------------------------------------------------------------
__global__ __launch_bounds__(256) void k_bscan(const int* __restrict__ cnt,
                                               int* __restrict__ bcnt, int* __restrict__ bstart,
                                               int* __restrict__ gcur) {
    __shared__ int sb[NB];
    const int tid = threadIdx.x;
    for (int s = 0; s < 3; ++s) {
        for (int b = tid; b < NB; b += 256) {
            int lo = b * BROWS;
            int hi = lo + BROWS; if (hi > NN) hi = NN;
            const int* p = cnt + s * NN;
            int sum = 0;
            for (int k = lo; k < hi; k += 4) {
                int4 v = *(const int4*)(p + k);
                sum += v.x + v.y + v.z + v.w;
            }
            sb[b] = sum;
        }
        __syncthreads();
        if (tid < 64) {
            int run = 0;
            for (int base = 0; base < NB; base += 64) {
                int idx = base + tid;
                int v = (idx < NB) ? sb[idx] : 0;
                int incl = v;
                #pragma unroll
                for (int off = 1; off < 64; off <<= 1) {
                    int u = __shfl_up(incl, off);
                    if (tid >= off) incl += u;
                }
                if (idx < NB) {
                    int st = run + incl - v;
                    bcnt[s * NB + idx] = v;
                    bstart[s * NB + idx] = st;
                    gcur[s * NB + idx] = st;
                }
                run += __shfl(incl, 63);
            }
        }
        __syncthreads();
    }
}

// ---------------------------------------------------------------------------
// Partition edges into dst-buckets. Chunked multisplit: LDS-stage 8192 edges,
// LDS histogram, one global atomic per (chunk,bucket) to claim a contiguous
// range, then write packed (dlow<<17 | src) entries in ~contiguous runs.
// ---------------------------------------------------------------------------
__global__ __launch_bounds__(256) void k_bscat(const int* __restrict__ e0, const int* __restrict__ e1,
                                               const int* __restrict__ e2,
                                               int* __restrict__ gcur, int* __restrict__ gpacked) {
    __shared__ int lpack[CHUNK];
    __shared__ unsigned short lbkt[CHUNK];
    __shared__ int hist[NB];
    __shared__ int lbase[NB];
    __shared__ int lcur[NB];
    const int tid = threadIdx.x;
    const int set = blockIdx.x / NCHUNK;
    const int chunk = blockIdx.x % NCHUNK;
    const int* ei = (set == 0) ? e0 : (set == 1) ? e1 : e2;
    const int ebase = chunk * CHUNK;

    for (int b = tid; b < NB; b += 256) { hist[b] = 0; lcur[b] = 0; }
    __syncthreads();

    #pragma unroll
    for (int j = 0; j < CHUNK / 256; ++j) {
        int k = tid + j * 256;
        int e = ebase + k;
        if (e < NE) {
            int s = ei[e];
            int d = ei[NE + e];
            int b = d >> 7;
            lpack[k] = ((d & 127) << 17) | s;
            lbkt[k] = (unsigned short)b;
            atomicAdd(&hist[b], 1);
        } else {
            lbkt[k] = 0xFFFFu;
        }
    }
    __syncthreads();
    for (int b = tid; b < NB; b += 256) {
        int h = hist[b];
        if (h > 0) lbase[b] = atomicAdd(&gcur[set * NB + b], h);
    }
    __syncthreads();
    int* gp = gpacked + (size_t)set * NE;
    #pragma unroll
    for (int j = 0; j < CHUNK / 256; ++j) {
        int k = tid + j * 256;
        unsigned short b = lbkt[k];
        if (b != 0xFFFFu) {
            int pos = lbase[b] + atomicAdd(&lcur[b], 1);
            gp[pos] = lpack[k];
        }
    }
}

// ---------------------------------------------------------------------------
// LGConv, bucket-parallel: block = one bucket of 128 dst rows held in LDS.
// 16 lanes per edge (float4 each), 32 edge streams per block, ds_add_f32
// accumulation, coalesced scaled write-out. No per-row CSR needed.
// ---------------------------------------------------------------------------
__global__ __launch_bounds__(512) void k_conv(const float* __restrict__ x, float* __restrict__ y,
                                              const int* __restrict__ gpacked,
                                              const int* __restrict__ bstart, const int* __restrict__ bcnt,
                                              const float* __restrict__ dinv) {
    __shared__ float acc[BROWS][64];    // 32 KB
    const int tid = threadIdx.x;
    const int b = blockIdx.x;
    for (int k = tid; k < BROWS * 64; k += 512) ((float*)acc)[k] = 0.f;
    __syncthreads();

    const int n = bcnt[b];
    const int* lst = gpacked + bstart[b];
    const int slot = tid >> 4;      // 32 edge streams
    const int fq = tid & 15;        // feature quad
    int i = slot;
    for (; i + 32 < n; i += 64) {
        int p0 = lst[i], p1 = lst[i + 32];
        int s0 = p0 & 0x1FFFF, s1 = p1 & 0x1FFFF;
        int d0 = (p0 >> 17) & 127, d1 = (p1 >> 17) & 127;
        float w0 = dinv[s0], w1 = dinv[s1];
        float4 v0 = *(const float4*)(x + s0 * 64 + fq * 4);
        float4 v1 = *(const float4*)(x + s1 * 64 + fq * 4);
        atomicAdd(&acc[d0][fq * 4 + 0], w0 * v0.x);
        atomicAdd(&acc[d0][fq * 4 + 1], w0 * v0.y);
        atomicAdd(&acc[d0][fq * 4 + 2], w0 * v0.z);
        atomicAdd(&acc[d0][fq * 4 + 3], w0 * v0.w);
        atomicAdd(&acc[d1][fq * 4 + 0], w1 * v1.x);
        atomicAdd(&acc[d1][fq * 4 + 1], w1 * v1.y);
        atomicAdd(&acc[d1][fq * 4 + 2], w1 * v1.z);
        atomicAdd(&acc[d1][fq * 4 + 3], w1 * v1.w);
    }
    if (i < n) {
        int p = lst[i];
        int s = p & 0x1FFFF;
        int d = (p >> 17) & 127;
        float w = dinv[s];
        float4 v = *(const float4*)(x + s * 64 + fq * 4);
        atomicAdd(&acc[d][fq * 4 + 0], w * v.x);
        atomicAdd(&acc[d][fq * 4 + 1], w * v.y);
        atomicAdd(&acc[d][fq * 4 + 2], w * v.z);
        atomicAdd(&acc[d][fq * 4 + 3], w * v.w);
    }
    __syncthreads();

    // write-out: 4 threads per row, 16 floats each, scaled by dinv[node]
    const int r = tid >> 2, cq = tid & 3;
    const int node = b * BROWS + r;
    if (node < NN) {
        float dn = dinv[node];
        float4* yp = (float4*)(y + (size_t)node * 64 + cq * 16);
        const float* ap = &acc[r][cq * 16];
        #pragma unroll
        for (int j = 0; j < 4; ++j) {
            float4 v = *(const float4*)(ap + j * 4);
            yp[j] = make_float4(dn * v.x, dn * v.y, dn * v.z, dn * v.w);
        }
    }
}

// ---------------------------------------------------------------------------
// Fused tail (unchanged from round 3). Xs node-major: conflict-free LDS.
// ---------------------------------------------------------------------------
__global__ __launch_bounds__(256) void k_final(const float* __restrict__ xt, const float* __restrict__ xy,
                                               const float* __restrict__ xc, const float* __restrict__ W1,
                                               const float* __restrict__ b1, const float* __restrict__ W2,
                                               const float* __restrict__ b2, float* __restrict__ out) {
    __shared__ float Xs[64][192];
    __shared__ float lg[64][3];
    const int tid = threadIdx.x;
    const int wave = tid >> 6, lane = tid & 63;
    const int nbase = blockIdx.x * 64;

    for (int g = 0; g < 16; ++g) {
        int m = g * 4 + wave;
        int node = nbase + m;
        float t = 0.f, y = 0.f, c = 0.f;
        if (node < NN) {
            int b = node * 64 + lane;
            t = xt[b]; y = xy[b]; c = xc[b];
        }
        float sst = t * t, ssy = y * y, ssc = c * c;
        #pragma unroll
        for (int off = 32; off > 0; off >>= 1) {
            sst += __shfl_xor(sst, off);
            ssy += __shfl_xor(ssy, off);
            ssc += __shfl_xor(ssc, off);
        }
        t /= fmaxf(sqrtf(sst), 1e-12f);
        y /= fmaxf(sqrtf(ssy), 1e-12f);
        c /= fmaxf(sqrtf(ssc), 1e-12f);
        Xs[m][lane]       = t;
        Xs[m][64 + lane]  = y;
        Xs[m][128 + lane] = c;
    }
    __syncthreads();

    const int cg = tid & 31;
    const int rg = tid >> 5;
    float acc[8][4];
    {
        float4 bv = *(const float4*)(b1 + cg * 4);
        #pragma unroll
        for (int i = 0; i < 8; ++i) {
            acc[i][0] = bv.x; acc[i][1] = bv.y; acc[i][2] = bv.z; acc[i][3] = bv.w;
        }
    }
    for (int kc = 0; kc < 192; kc += 4) {
        float4 xv[8];
        #pragma unroll
        for (int i = 0; i < 8; ++i) xv[i] = *(const float4*)&Xs[rg * 8 + i][kc];
        float4 w0 = *(const float4*)(W1 + (kc + 0) * 128 + cg * 4);
        float4 w1 = *(const float4*)(W1 + (kc + 1) * 128 + cg * 4);
        float4 w2 = *(const float4*)(W1 + (kc + 2) * 128 + cg * 4);
        float4 w3 = *(const float4*)(W1 + (kc + 3) * 128 + cg * 4);
        #pragma unroll
        for (int i = 0; i < 8; ++i) {
            float4 xi = xv[i];
            acc[i][0] = fmaf(xi.x, w0.x, acc[i][0]); acc[i][1] = fmaf(xi.x, w0.y, acc[i][1]);
            acc[i][2] = fmaf(xi.x, w0.z, acc[i][2]); acc[i][3] = fmaf(xi.x, w0.w, acc[i][3]);
            acc[i][0] = fmaf(xi.y, w1.x, acc[i][0]); acc[i][1] = fmaf(xi.y, w1.y, acc[i][1]);
            acc[i][2] = fmaf(xi.y, w1.z, acc[i][2]); acc[i][3] = fmaf(xi.y, w1.w, acc[i][3]);
            acc[i][0] = fmaf(xi.z, w2.x, acc[i][0]); acc[i][1] = fmaf(xi.z, w2.y, acc[i][1]);
            acc[i][2] = fmaf(xi.z, w2.z, acc[i][2]); acc[i][3] = fmaf(xi.z, w2.w, acc[i][3]);
            acc[i][0] = fmaf(xi.w, w3.x, acc[i][0]); acc[i][1] = fmaf(xi.w, w3.y, acc[i][1]);
            acc[i][2] = fmaf(xi.w, w3.z, acc[i][2]); acc[i][3] = fmaf(xi.w, w3.w, acc[i][3]);
        }
    }

    float w2c[4][3];
    #pragma unroll
    for (int j = 0; j < 4; ++j)
        #pragma unroll
        for (int q = 0; q < 3; ++q) w2c[j][q] = W2[(cg * 4 + j) * 3 + q];

    #pragma unroll
    for (int i = 0; i < 8; ++i) {
        float p0 = 0.f, p1 = 0.f, p2 = 0.f;
        #pragma unroll
        for (int j = 0; j < 4; ++j) {
            float h = fmaxf(acc[i][j], 0.f);
            p0 = fmaf(h, w2c[j][0], p0);
            p1 = fmaf(h, w2c[j][1], p1);
            p2 = fmaf(h, w2c[j][2], p2);
        }
        #pragma unroll
        for (int off = 16; off > 0; off >>= 1) {
            p0 += __shfl_xor(p0, off);
            p1 += __shfl_xor(p1, off);
            p2 += __shfl_xor(p2, off);
        }
        if (cg == 0) {
            lg[rg * 8 + i][0] = p0;
            lg[rg * 8 + i][1] = p1;
            lg[rg * 8 + i][2] = p2;
        }
    }
    __syncthreads();

    for (int g = 0; g < 16; ++g) {
        int m = g * 4 + wave;
        int node = nbase + m;
        if (node < NN) {
            float l0 = lg[m][0] + b2[0];
            float l1 = lg[m][1] + b2[1];
            float l2 = lg[m][2] + b2[2];
            float mx = fmaxf(l0, fmaxf(l1, l2));
            float e0 = __expf(l0 - mx), e1 = __expf(l1 - mx), e2 = __expf(l2 - mx);
            float inv = 1.0f / (e0 + e1 + e2);
            float t = Xs[m][lane], y = Xs[m][64 + lane], c = Xs[m][128 + lane];
            out[node * 64 + lane] = (e0 * t + e1 * y + e2 * c) * inv;
        }
    }
}

// ---------------------------------------------------------------------------
extern "C" void kernel_launch(void* const* d_in, const int* in_sizes, int n_in,
                              void* d_out, int out_size, void* d_ws, size_t ws_size,
                              hipStream_t stream) {
    const float* init_feat = (const float*)d_in[0];
    const float* W1 = (const float*)d_in[1];
    const float* b1 = (const float*)d_in[2];
    const float* W2 = (const float*)d_in[3];
    const float* b2 = (const float*)d_in[4];
    const int* ei[3] = {(const int*)d_in[5], (const int*)d_in[6], (const int*)d_in[7]}; // title, year, cat

    float* TMP = (float*)d_out;   // d_out doubles as ping-pong temp (fully rewritten before reads)

    float* B1 = (float*)d_ws;                     // title out   [N*64]
    float* B2 = B1 + (size_t)NN * 64;             // year out
    float* B3 = B2 + (size_t)NN * 64;             // cat temp
    float* dinvA = B3 + (size_t)NN * 64;          // [3*N]
    int* cntA = (int*)(dinvA + 3 * NN);           // [3*N]
    int* bcntA = cntA + 3 * NN;                   // [3*NB]
    int* bstartA = bcntA + 3 * NB;                // [3*NB]
    int* gcurA = bstartA + 3 * NB;                // [3*NB]
    int* gpackedA = gcurA + 3 * NB;               // [3*NE]

    const int TB = 256;
    const int e3Grid = (3 * NE + TB - 1) / TB;
    const int finalGrid = (NN + 63) / 64;

    hipMemsetAsync(cntA, 0, (size_t)(3 * NN) * sizeof(int), stream);

    k_cnt3<<<e3Grid, TB, 0, stream>>>(ei[0], ei[1], ei[2], cntA);
    k_dinv<<<(3 * NN + TB - 1) / TB, TB, 0, stream>>>(cntA, dinvA);
    k_bscan<<<1, TB, 0, stream>>>(cntA, bcntA, bstartA, gcurA);
    k_bscat<<<3 * NCHUNK, TB, 0, stream>>>(ei[0], ei[1], ei[2], gcurA, gpackedA);

    #define CONV(xp, yp, s) \
        k_conv<<<NB, 512, 0, stream>>>((xp), (yp), gpackedA + (size_t)(s) * NE, \
                                       bstartA + (s) * NB, bcntA + (s) * NB, dinvA + (s) * NN)
    CONV(init_feat, TMP, 0);   // title conv 1
    CONV(TMP, B1, 0);          // title conv 2 -> B1
    CONV(init_feat, B2, 1);    // year conv    -> B2
    CONV(init_feat, TMP, 2);   // cat conv 1
    CONV(TMP, B3, 2);          // cat conv 2
    CONV(B3, TMP, 2);          // cat conv 3   -> TMP (= d_out)
    #undef CONV

    k_final<<<finalGrid, TB, 0, stream>>>(B1, B2, TMP, W1, b1, W2, b2, TMP);
}

// Round 5
// 666.113 us; speedup vs baseline: 5.2905x; 5.2905x over previous
//
#include <hip/hip_runtime.h>

// PDA_GNN: 3-branch LightGCN. CSR built via bucket-multisplit (coalesced writes)
// + per-bucket sort; convs are latency-pipelined per-row gathers with register
// accumulation; fused normalize/concat/MLP/softmax tail. N=100000, E=1250000.

constexpr int NN = 100000;
constexpr int NE = 1250000;
constexpr int BROWS = 128;                       // dst nodes per bucket
constexpr int NB = (NN + BROWS - 1) / BROWS;     // 782 buckets
constexpr int CHUNK = 8192;                      // edges per partition block
constexpr int NCHUNK = (NE + CHUNK - 1) / CHUNK; // 153

// ---------------------------------------------------------------------------
// In-degree count for all 3 edge sets
// ---------------------------------------------------------------------------
__global__ __launch_bounds__(256) void k_cnt3(const int* __restrict__ e0, const int* __restrict__ e1,
                                              const int* __restrict__ e2, int* __restrict__ cnt) {
    int i = blockIdx.x * 256 + threadIdx.x;
    if (i < NE) atomicAdd(&cnt[e0[NE + i]], 1);
    else if (i < 2 * NE) atomicAdd(&cnt[NN + e1[NE + i - NE]], 1);
    else if (i < 3 * NE) atomicAdd(&cnt[2 * NN + e2[NE + i - 2 * NE]], 1);
}

__global__ __launch_bounds__(256) void k_dinv(const int* __restrict__ cnt, float* __restrict__ dinv) {
    int i = blockIdx.x * 256 + threadIdx.x;
    if (i < 3 * NN) {
        int c = cnt[i];
        dinv[i] = (c > 0) ? (1.0f / sqrtf((float)c)) : 0.0f;
    }
}

// ---------------------------------------------------------------------------
// Bucket totals + exclusive scan -> bstart, gcur (single block)
// ---------------------------------------------------------------------------
__global__ __launch_bounds__(256) void k_bscan(const int* __restrict__ cnt,
                                               int* __restrict__ bstart, int* __restrict__ gcur) {
    __shared__ int sb[NB];
    const int tid = threadIdx.x;
    for (int s = 0; s < 3; ++s) {
        for (int b = tid; b < NB; b += 256) {
            int lo = b * BROWS;
            int hi = lo + BROWS; if (hi > NN) hi = NN;
            const int* p = cnt + s * NN;
            int sum = 0;
            for (int k = lo; k < hi; k += 4) {
                int4 v = *(const int4*)(p + k);
                sum += v.x + v.y + v.z + v.w;
            }
            sb[b] = sum;
        }
        __syncthreads();
        if (tid < 64) {
            int run = 0;
            for (int base = 0; base < NB; base += 64) {
                int idx = base + tid;
                int v = (idx < NB) ? sb[idx] : 0;
                int incl = v;
                #pragma unroll
                for (int off = 1; off < 64; off <<= 1) {
                    int u = __shfl_up(incl, off);
                    if (tid >= off) incl += u;
                }
                if (idx < NB) {
                    int st = run + incl - v;
                    bstart[s * NB + idx] = st;
                    gcur[s * NB + idx] = st;
                }
                run += __shfl(incl, 63);
            }
        }
        __syncthreads();
    }
}

// ---------------------------------------------------------------------------
// Per-node CSR start: bstart[bucket] + within-bucket prefix of cnt.
// One wave per (set,bucket); lane handles 2 nodes.
// ---------------------------------------------------------------------------
__global__ __launch_bounds__(256) void k_rowstart(const int* __restrict__ cnt,
                                                  const int* __restrict__ bstart,
                                                  int* __restrict__ rowstart) {
    const int wid = blockIdx.x * 4 + (threadIdx.x >> 6);
    if (wid >= 3 * NB) return;
    const int lane = threadIdx.x & 63;
    const int set = wid / NB, b = wid % NB;
    const int n0 = b * BROWS + 2 * lane;
    const int n1 = n0 + 1;
    int v0 = (n0 < NN) ? cnt[set * NN + n0] : 0;
    int v1 = (n1 < NN) ? cnt[set * NN + n1] : 0;
    int pair = v0 + v1;
    int incl = pair;
    #pragma unroll
    for (int off = 1; off < 64; off <<= 1) {
        int u = __shfl_up(incl, off);
        if (lane >= off) incl += u;
    }
    int excl = incl - pair;
    int base = bstart[set * NB + b];
    if (n0 < NN) rowstart[set * NN + n0] = base + excl;
    if (n1 < NN) rowstart[set * NN + n1] = base + excl + v0;
}

// ---------------------------------------------------------------------------
// Bucket multisplit: LDS-stage 8192 edges, LDS histogram, one global atomic
// per (chunk,bucket), write packed (dlow<<17 | src) in ~contiguous runs.
// ---------------------------------------------------------------------------
__global__ __launch_bounds__(256) void k_bscat(const int* __restrict__ e0, const int* __restrict__ e1,
                                               const int* __restrict__ e2,
                                               int* __restrict__ gcur, int* __restrict__ gpacked) {
    __shared__ int lpack[CHUNK];
    __shared__ unsigned short lbkt[CHUNK];
    __shared__ int hist[NB];
    __shared__ int lbase[NB];
    __shared__ int lcur[NB];
    const int tid = threadIdx.x;
    const int set = blockIdx.x / NCHUNK;
    const int chunk = blockIdx.x % NCHUNK;
    const int* ei = (set == 0) ? e0 : (set == 1) ? e1 : e2;
    const int ebase = chunk * CHUNK;

    for (int b = tid; b < NB; b += 256) { hist[b] = 0; lcur[b] = 0; }
    __syncthreads();

    #pragma unroll
    for (int j = 0; j < CHUNK / 256; ++j) {
        int k = tid + j * 256;
        int e = ebase + k;
        if (e < NE) {
            int s = ei[e];
            int d = ei[NE + e];
            int b = d >> 7;
            lpack[k] = ((d & 127) << 17) | s;
            lbkt[k] = (unsigned short)b;
            atomicAdd(&hist[b], 1);
        } else {
            lbkt[k] = 0xFFFFu;
        }
    }
    __syncthreads();
    for (int b = tid; b < NB; b += 256) {
        int h = hist[b];
        if (h > 0) lbase[b] = atomicAdd(&gcur[set * NB + b], h);
    }
    __syncthreads();
    int* gp = gpacked + (size_t)set * NE;
    #pragma unroll
    for (int j = 0; j < CHUNK / 256; ++j) {
        int k = tid + j * 256;
        unsigned short b = lbkt[k];
        if (b != 0xFFFFu) {
            int pos = lbase[b] + atomicAdd(&lcur[b], 1);
            gp[pos] = lpack[k];
        }
    }
}

// ---------------------------------------------------------------------------
// Per-bucket sort into true per-row CSR. Writes stay inside the bucket's
// contiguous window -> cache-friendly. Block per (set,bucket).
// ---------------------------------------------------------------------------
__global__ __launch_bounds__(256) void k_bsort(const int* __restrict__ gpacked,
                                               const int* __restrict__ bstart,
                                               const int* __restrict__ gcur,   // end cursors = bstart+count
                                               const int* __restrict__ rowstart,
                                               int* __restrict__ csr) {
    __shared__ int lcur[BROWS];
    const int tid = threadIdx.x;
    const int set = blockIdx.x / NB, b = blockIdx.x % NB;
    if (tid < BROWS) lcur[tid] = 0;
    __syncthreads();
    const int base = bstart[set * NB + b];
    const int n = gcur[set * NB + b] - base;       // bucket edge count
    const int* gp = gpacked + (size_t)set * NE + base;
    const int* rs = rowstart + set * NN + b * BROWS;
    int* cs = csr + (size_t)set * NE;
    for (int k = tid; k < n; k += 256) {
        int p = gp[k];
        int d = (p >> 17) & 127;
        int s = p & 0x1FFFF;
        int pos = rs[d] + atomicAdd(&lcur[d], 1);
        cs[pos] = s;
    }
}

// ---------------------------------------------------------------------------
// LGConv gather, 4-deep pipelined: one wave per dst node, 16 lanes per edge
// (float4 each), each slot issues 4 independent clamped/masked row loads per
// iteration (16 rows in flight per wave). Register accumulation + shfl combine.
// PRE: input already carries dinv[src] factor (chained conv). SQOUT: emit
// dinv^2-scaled output to feed the next conv of the same chain.
// ---------------------------------------------------------------------------
template<bool PRE, bool SQOUT>
__global__ __launch_bounds__(256) void k_gather(const float* __restrict__ x, float* __restrict__ y,
                                                const int* __restrict__ csr, const int* __restrict__ rowstart,
                                                const int* __restrict__ cnt, const float* __restrict__ dinv) {
    const int node = blockIdx.x * 4 + (threadIdx.x >> 6);
    const int lane = threadIdx.x & 63;
    const int sub = lane >> 4;
    const int fq = lane & 15;
    const int n = cnt[node];
    float a0 = 0.f, a1 = 0.f, a2 = 0.f, a3 = 0.f;
    if (n > 0) {
        const int* lst = csr + rowstart[node];
        for (int i = sub; i < n; i += 16) {
            const int j1 = i + 4, j2 = i + 8, j3 = i + 12;
            const int s0 = lst[i];
            const int s1 = lst[j1 < n ? j1 : n - 1];
            const int s2 = lst[j2 < n ? j2 : n - 1];
            const int s3 = lst[j3 < n ? j3 : n - 1];
            float w0, w1, w2, w3;
            if (PRE) {
                w0 = 1.f;
                w1 = (j1 < n) ? 1.f : 0.f;
                w2 = (j2 < n) ? 1.f : 0.f;
                w3 = (j3 < n) ? 1.f : 0.f;
            } else {
                w0 = dinv[s0];
                w1 = (j1 < n) ? dinv[s1] : 0.f;
                w2 = (j2 < n) ? dinv[s2] : 0.f;
                w3 = (j3 < n) ? dinv[s3] : 0.f;
            }
            const float4 v0 = *(const float4*)(x + (size_t)s0 * 64 + fq * 4);
            const float4 v1 = *(const float4*)(x + (size_t)s1 * 64 + fq * 4);
            const float4 v2 = *(const float4*)(x + (size_t)s2 * 64 + fq * 4);
            const float4 v3 = *(const float4*)(x + (size_t)s3 * 64 + fq * 4);
            a0 = fmaf(w0, v0.x, a0); a1 = fmaf(w0, v0.y, a1);
            a2 = fmaf(w0, v0.z, a2); a3 = fmaf(w0, v0.w, a3);
            a0 = fmaf(w1, v1.x, a0); a1 = fmaf(w1, v1.y, a1);
            a2 = fmaf(w1, v1.z, a2); a3 = fmaf(w1, v1.w, a3);
            a0 = fmaf(w2, v2.x, a0); a1 = fmaf(w2, v2.y, a1);
            a2 = fmaf(w2, v2.z, a2); a3 = fmaf(w2, v2.w, a3);
            a0 = fmaf(w3, v3.x, a0); a1 = fmaf(w3, v3.y, a1);
            a2 = fmaf(w3, v3.z, a2); a3 = fmaf(w3, v3.w, a3);
        }
    }
    a0 += __shfl_xor(a0, 16); a1 += __shfl_xor(a1, 16);
    a2 += __shfl_xor(a2, 16); a3 += __shfl_xor(a3, 16);
    a0 += __shfl_xor(a0, 32); a1 += __shfl_xor(a1, 32);
    a2 += __shfl_xor(a2, 32); a3 += __shfl_xor(a3, 32);
    if (sub == 0) {
        float dn = dinv[node];
        float sc = SQOUT ? dn * dn : dn;
        *(float4*)(y + (size_t)node * 64 + fq * 4) =
            make_float4(sc * a0, sc * a1, sc * a2, sc * a3);
    }
}

// ---------------------------------------------------------------------------
// Fused tail (round-3 version; node-major Xs, conflict-free LDS).
// ---------------------------------------------------------------------------
__global__ __launch_bounds__(256) void k_final(const float* __restrict__ xt, const float* __restrict__ xy,
                                               const float* __restrict__ xc, const float* __restrict__ W1,
                                               const float* __restrict__ b1, const float* __restrict__ W2,
                                               const float* __restrict__ b2, float* __restrict__ out) {
    __shared__ float Xs[64][192];
    __shared__ float lg[64][3];
    const int tid = threadIdx.x;
    const int wave = tid >> 6, lane = tid & 63;
    const int nbase = blockIdx.x * 64;

    for (int g = 0; g < 16; ++g) {
        int m = g * 4 + wave;
        int node = nbase + m;
        float t = 0.f, y = 0.f, c = 0.f;
        if (node < NN) {
            int b = node * 64 + lane;
            t = xt[b]; y = xy[b]; c = xc[b];
        }
        float sst = t * t, ssy = y * y, ssc = c * c;
        #pragma unroll
        for (int off = 32; off > 0; off >>= 1) {
            sst += __shfl_xor(sst, off);
            ssy += __shfl_xor(ssy, off);
            ssc += __shfl_xor(ssc, off);
        }
        t /= fmaxf(sqrtf(sst), 1e-12f);
        y /= fmaxf(sqrtf(ssy), 1e-12f);
        c /= fmaxf(sqrtf(ssc), 1e-12f);
        Xs[m][lane]       = t;
        Xs[m][64 + lane]  = y;
        Xs[m][128 + lane] = c;
    }
    __syncthreads();

    const int cg = tid & 31;
    const int rg = tid >> 5;
    float acc[8][4];
    {
        float4 bv = *(const float4*)(b1 + cg * 4);
        #pragma unroll
        for (int i = 0; i < 8; ++i) {
            acc[i][0] = bv.x; acc[i][1] = bv.y; acc[i][2] = bv.z; acc[i][3] = bv.w;
        }
    }
    for (int kc = 0; kc < 192; kc += 4) {
        float4 xv[8];
        #pragma unroll
        for (int i = 0; i < 8; ++i) xv[i] = *(const float4*)&Xs[rg * 8 + i][kc];
        float4 w0 = *(const float4*)(W1 + (kc + 0) * 128 + cg * 4);
        float4 w1 = *(const float4*)(W1 + (kc + 1) * 128 + cg * 4);
        float4 w2 = *(const float4*)(W1 + (kc + 2) * 128 + cg * 4);
        float4 w3 = *(const float4*)(W1 + (kc + 3) * 128 + cg * 4);
        #pragma unroll
        for (int i = 0; i < 8; ++i) {
            float4 xi = xv[i];
            acc[i][0] = fmaf(xi.x, w0.x, acc[i][0]); acc[i][1] = fmaf(xi.x, w0.y, acc[i][1]);
            acc[i][2] = fmaf(xi.x, w0.z, acc[i][2]); acc[i][3] = fmaf(xi.x, w0.w, acc[i][3]);
            acc[i][0] = fmaf(xi.y, w1.x, acc[i][0]); acc[i][1] = fmaf(xi.y, w1.y, acc[i][1]);
            acc[i][2] = fmaf(xi.y, w1.z, acc[i][2]); acc[i][3] = fmaf(xi.y, w1.w, acc[i][3]);
            acc[i][0] = fmaf(xi.z, w2.x, acc[i][0]); acc[i][1] = fmaf(xi.z, w2.y, acc[i][1]);
            acc[i][2] = fmaf(xi.z, w2.z, acc[i][2]); acc[i][3] = fmaf(xi.z, w2.w, acc[i][3]);
            acc[i][0] = fmaf(xi.w, w3.x, acc[i][0]); acc[i][1] = fmaf(xi.w, w3.y, acc[i][1]);
            acc[i][2] = fmaf(xi.w, w3.z, acc[i][2]); acc[i][3] = fmaf(xi.w, w3.w, acc[i][3]);
        }
    }

    float w2c[4][3];
    #pragma unroll
    for (int j = 0; j < 4; ++j)
        #pragma unroll
        for (int q = 0; q < 3; ++q) w2c[j][q] = W2[(cg * 4 + j) * 3 + q];

    #pragma unroll
    for (int i = 0; i < 8; ++i) {
        float p0 = 0.f, p1 = 0.f, p2 = 0.f;
        #pragma unroll
        for (int j = 0; j < 4; ++j) {
            float h = fmaxf(acc[i][j], 0.f);
            p0 = fmaf(h, w2c[j][0], p0);
            p1 = fmaf(h, w2c[j][1], p1);
            p2 = fmaf(h, w2c[j][2], p2);
        }
        #pragma unroll
        for (int off = 16; off > 0; off >>= 1) {
            p0 += __shfl_xor(p0, off);
            p1 += __shfl_xor(p1, off);
            p2 += __shfl_xor(p2, off);
        }
        if (cg == 0) {
            lg[rg * 8 + i][0] = p0;
            lg[rg * 8 + i][1] = p1;
            lg[rg * 8 + i][2] = p2;
        }
    }
    __syncthreads();

    for (int g = 0; g < 16; ++g) {
        int m = g * 4 + wave;
        int node = nbase + m;
        if (node < NN) {
            float l0 = lg[m][0] + b2[0];
            float l1 = lg[m][1] + b2[1];
            float l2 = lg[m][2] + b2[2];
            float mx = fmaxf(l0, fmaxf(l1, l2));
            float e0 = __expf(l0 - mx), e1 = __expf(l1 - mx), e2 = __expf(l2 - mx);
            float inv = 1.0f / (e0 + e1 + e2);
            float t = Xs[m][lane], y = Xs[m][64 + lane], c = Xs[m][128 + lane];
            out[node * 64 + lane] = (e0 * t + e1 * y + e2 * c) * inv;
        }
    }
}

// ---------------------------------------------------------------------------
extern "C" void kernel_launch(void* const* d_in, const int* in_sizes, int n_in,
                              void* d_out, int out_size, void* d_ws, size_t ws_size,
                              hipStream_t stream) {
    const float* init_feat = (const float*)d_in[0];
    const float* W1 = (const float*)d_in[1];
    const float* b1 = (const float*)d_in[2];
    const float* W2 = (const float*)d_in[3];
    const float* b2 = (const float*)d_in[4];
    const int* ei[3] = {(const int*)d_in[5], (const int*)d_in[6], (const int*)d_in[7]}; // title, year, cat

    float* TMP = (float*)d_out;   // d_out doubles as a temp (fully rewritten before reads)

    float* B1 = (float*)d_ws;                     // [N*64]
    float* B2 = B1 + (size_t)NN * 64;             // [N*64]
    float* dinvA = B2 + (size_t)NN * 64;          // [3*N]
    int* cntA = (int*)(dinvA + 3 * NN);           // [3*N]
    int* rowA = cntA + 3 * NN;                    // [3*N]
    int* gpackedA = rowA + 3 * NN;                // [3*E]
    int* csrA = gpackedA + (size_t)3 * NE;        // [3*E]
    int* bstartA = csrA + (size_t)3 * NE;         // [3*NB]
    int* gcurA = bstartA + 3 * NB;                // [3*NB]

    const int TB = 256;
    const int e3Grid = (3 * NE + TB - 1) / TB;
    const int finalGrid = (NN + 63) / 64;

    hipMemsetAsync(cntA, 0, (size_t)(3 * NN) * sizeof(int), stream);

    k_cnt3<<<e3Grid, TB, 0, stream>>>(ei[0], ei[1], ei[2], cntA);
    k_dinv<<<(3 * NN + TB - 1) / TB, TB, 0, stream>>>(cntA, dinvA);
    k_bscan<<<1, TB, 0, stream>>>(cntA, bstartA, gcurA);
    k_rowstart<<<(3 * NB + 3) / 4, TB, 0, stream>>>(cntA, bstartA, rowA);
    k_bscat<<<3 * NCHUNK, TB, 0, stream>>>(ei[0], ei[1], ei[2], gcurA, gpackedA);
    k_bsort<<<3 * NB, TB, 0, stream>>>(gpackedA, bstartA, gcurA, rowA, csrA);

    // convs: PRE = input pre-scaled by dinv, SQOUT = emit dinv^2-scaled output
    #define CONV(PRE, SQ, xp, yp, s) \
        k_gather<PRE, SQ><<<NN / 4, TB, 0, stream>>>((xp), (yp), csrA + (size_t)(s) * NE, \
                                                     rowA + (s) * NN, cntA + (s) * NN, dinvA + (s) * NN)
    // cat chain (set 2): init -> B1 -> B2 -> TMP
    CONV(false, true,  init_feat, B1, 2);
    CONV(true,  true,  B1,        B2, 2);
    CONV(true,  false, B2,        TMP, 2);
    // title chain (set 0): init -> B1 -> B2
    CONV(false, true,  init_feat, B1, 0);
    CONV(true,  false, B1,        B2, 0);
    // year (set 1): init -> B1
    CONV(false, false, init_feat, B1, 1);
    #undef CONV

    // xt=title(B2), xy=year(B1), xc=cat(TMP); writes d_out (row-local alias safe)
    k_final<<<finalGrid, TB, 0, stream>>>(B2, B1, TMP, W1, b1, W2, b2, TMP);
}

// Round 6
// 495.110 us; speedup vs baseline: 7.1177x; 1.3454x over previous
//
#include <hip/hip_runtime.h>

// PDA_GNN: 3-branch LightGCN. Atomic-free-ish CSR build: bucket histograms in
// LDS -> multisplit -> per-bucket finalize (counts/dinv/rowstart/CSR, all
// coalesced). Convs: latency-pipelined per-row gathers, register accumulation.
// Fused normalize/concat/MLP/softmax tail. N=100000, E=1250000, D=64.

constexpr int NN = 100000;
constexpr int NE = 1250000;
constexpr int BROWS = 128;                       // dst nodes per bucket
constexpr int NB = (NN + BROWS - 1) / BROWS;     // 782 buckets
constexpr int CHUNK = 8192;                      // edges per partition block
constexpr int NCHUNK = (NE + CHUNK - 1) / CHUNK; // 153

// ---------------------------------------------------------------------------
// Per-chunk bucket histogram -> btot (few clustered global atomics)
// ---------------------------------------------------------------------------
__global__ __launch_bounds__(256) void k_bhist(const int* __restrict__ e0, const int* __restrict__ e1,
                                               const int* __restrict__ e2, int* __restrict__ btot) {
    __shared__ int hist[NB];
    const int tid = threadIdx.x;
    const int set = blockIdx.x / NCHUNK;
    const int chunk = blockIdx.x % NCHUNK;
    const int* ei = (set == 0) ? e0 : (set == 1) ? e1 : e2;
    const int ebase = chunk * CHUNK;
    for (int b = tid; b < NB; b += 256) hist[b] = 0;
    __syncthreads();
    #pragma unroll
    for (int j = 0; j < CHUNK / 256; ++j) {
        int e = ebase + tid + j * 256;
        if (e < NE) atomicAdd(&hist[ei[NE + e] >> 7], 1);
    }
    __syncthreads();
    for (int b = tid; b < NB; b += 256) {
        int h = hist[b];
        if (h > 0) atomicAdd(&btot[set * NB + b], h);
    }
}

// ---------------------------------------------------------------------------
// Scan bucket totals -> bstart, gcur (single block)
// ---------------------------------------------------------------------------
__global__ __launch_bounds__(256) void k_bscan2(const int* __restrict__ btot,
                                                int* __restrict__ bstart, int* __restrict__ gcur) {
    const int tid = threadIdx.x;
    if (tid >= 64) return;
    for (int s = 0; s < 3; ++s) {
        int run = 0;
        for (int base = 0; base < NB; base += 64) {
            int idx = base + tid;
            int v = (idx < NB) ? btot[s * NB + idx] : 0;
            int incl = v;
            #pragma unroll
            for (int off = 1; off < 64; off <<= 1) {
                int u = __shfl_up(incl, off);
                if (tid >= off) incl += u;
            }
            if (idx < NB) {
                int st = run + incl - v;
                bstart[s * NB + idx] = st;
                gcur[s * NB + idx] = st;
            }
            run += __shfl(incl, 63);
        }
    }
}

// ---------------------------------------------------------------------------
// Bucket multisplit: LDS-stage 8192 edges, LDS histogram, one global atomic
// per (chunk,bucket), write packed (dlow<<17 | src) in ~contiguous runs.
// ---------------------------------------------------------------------------
__global__ __launch_bounds__(256) void k_bscat(const int* __restrict__ e0, const int* __restrict__ e1,
                                               const int* __restrict__ e2,
                                               int* __restrict__ gcur, int* __restrict__ gpacked) {
    __shared__ int lpack[CHUNK];
    __shared__ unsigned short lbkt[CHUNK];
    __shared__ int hist[NB];
    __shared__ int lbase[NB];
    __shared__ int lcur[NB];
    const int tid = threadIdx.x;
    const int set = blockIdx.x / NCHUNK;
    const int chunk = blockIdx.x % NCHUNK;
    const int* ei = (set == 0) ? e0 : (set == 1) ? e1 : e2;
    const int ebase = chunk * CHUNK;

    for (int b = tid; b < NB; b += 256) { hist[b] = 0; lcur[b] = 0; }
    __syncthreads();

    #pragma unroll
    for (int j = 0; j < CHUNK / 256; ++j) {
        int k = tid + j * 256;
        int e = ebase + k;
        if (e < NE) {
            int s = ei[e];
            int d = ei[NE + e];
            int b = d >> 7;
            lpack[k] = ((d & 127) << 17) | s;
            lbkt[k] = (unsigned short)b;
            atomicAdd(&hist[b], 1);
        } else {
            lbkt[k] = 0xFFFFu;
        }
    }
    __syncthreads();
    for (int b = tid; b < NB; b += 256) {
        int h = hist[b];
        if (h > 0) lbase[b] = atomicAdd(&gcur[set * NB + b], h);
    }
    __syncthreads();
    int* gp = gpacked + (size_t)set * NE;
    #pragma unroll
    for (int j = 0; j < CHUNK / 256; ++j) {
        int k = tid + j * 256;
        unsigned short b = lbkt[k];
        if (b != 0xFFFFu) {
            int pos = lbase[b] + atomicAdd(&lcur[b], 1);
            gp[pos] = lpack[k];
        }
    }
}

// ---------------------------------------------------------------------------
// Per-bucket finalize: LDS histogram of the bucket window -> per-node cnt /
// dinv / rowstart (coalesced writes) + scatter window into per-row CSR.
// Block per (set,bucket).
// ---------------------------------------------------------------------------
__global__ __launch_bounds__(256) void k_bfin(const int* __restrict__ gpacked,
                                              const int* __restrict__ bstart,
                                              const int* __restrict__ gcur,   // end cursors
                                              int* __restrict__ cnt, float* __restrict__ dinv,
                                              int* __restrict__ rowstart, int* __restrict__ csr) {
    __shared__ int hist[BROWS];
    __shared__ int rst[BROWS];    // absolute csr start per row
    __shared__ int lcur[BROWS];
    const int tid = threadIdx.x;
    const int set = blockIdx.x / NB, b = blockIdx.x % NB;
    if (tid < BROWS) { hist[tid] = 0; lcur[tid] = 0; }
    __syncthreads();

    const int base = bstart[set * NB + b];
    const int n = gcur[set * NB + b] - base;
    const int* gp = gpacked + (size_t)set * NE + base;

    for (int k = tid; k < n; k += 256) atomicAdd(&hist[(gp[k] >> 17) & 127], 1);
    __syncthreads();

    if (tid < 64) {
        int v0 = hist[tid], v1 = hist[64 + tid];
        int i0 = v0;
        #pragma unroll
        for (int off = 1; off < 64; off <<= 1) {
            int u = __shfl_up(i0, off);
            if (tid >= off) i0 += u;
        }
        int t0 = __shfl(i0, 63);
        int i1 = v1;
        #pragma unroll
        for (int off = 1; off < 64; off <<= 1) {
            int u = __shfl_up(i1, off);
            if (tid >= off) i1 += u;
        }
        rst[tid] = base + i0 - v0;
        rst[64 + tid] = base + t0 + i1 - v1;
    }
    __syncthreads();

    if (tid < BROWS) {
        int node = b * BROWS + tid;
        if (node < NN) {
            int c = hist[tid];
            cnt[set * NN + node] = c;
            dinv[set * NN + node] = (c > 0) ? (1.0f / sqrtf((float)c)) : 0.0f;
            rowstart[set * NN + node] = rst[tid];
        }
    }

    int* cs = csr + (size_t)set * NE;
    for (int k = tid; k < n; k += 256) {
        int p = gp[k];
        int d = (p >> 17) & 127;
        int pos = rst[d] + atomicAdd(&lcur[d], 1);
        cs[pos] = p & 0x1FFFF;
    }
}

// ---------------------------------------------------------------------------
// LGConv gather, 4-deep pipelined: one wave per dst node, 16 lanes per edge
// (float4 each). Register accumulation + shfl combine. PRE: input already
// carries dinv[src]; SQOUT: emit dinv^2-scaled output for the chained conv.
// ---------------------------------------------------------------------------
template<bool PRE, bool SQOUT>
__global__ __launch_bounds__(256) void k_gather(const float* __restrict__ x, float* __restrict__ y,
                                                const int* __restrict__ csr, const int* __restrict__ rowstart,
                                                const int* __restrict__ cnt, const float* __restrict__ dinv) {
    const int node = blockIdx.x * 4 + (threadIdx.x >> 6);
    const int lane = threadIdx.x & 63;
    const int sub = lane >> 4;
    const int fq = lane & 15;
    const int n = cnt[node];
    float a0 = 0.f, a1 = 0.f, a2 = 0.f, a3 = 0.f;
    if (n > 0) {
        const int* lst = csr + rowstart[node];
        for (int i = sub; i < n; i += 16) {
            const int j1 = i + 4, j2 = i + 8, j3 = i + 12;
            const int s0 = lst[i];
            const int s1 = lst[j1 < n ? j1 : n - 1];
            const int s2 = lst[j2 < n ? j2 : n - 1];
            const int s3 = lst[j3 < n ? j3 : n - 1];
            float w0, w1, w2, w3;
            if (PRE) {
                w0 = 1.f;
                w1 = (j1 < n) ? 1.f : 0.f;
                w2 = (j2 < n) ? 1.f : 0.f;
                w3 = (j3 < n) ? 1.f : 0.f;
            } else {
                w0 = dinv[s0];
                w1 = (j1 < n) ? dinv[s1] : 0.f;
                w2 = (j2 < n) ? dinv[s2] : 0.f;
                w3 = (j3 < n) ? dinv[s3] : 0.f;
            }
            const float4 v0 = *(const float4*)(x + (size_t)s0 * 64 + fq * 4);
            const float4 v1 = *(const float4*)(x + (size_t)s1 * 64 + fq * 4);
            const float4 v2 = *(const float4*)(x + (size_t)s2 * 64 + fq * 4);
            const float4 v3 = *(const float4*)(x + (size_t)s3 * 64 + fq * 4);
            a0 = fmaf(w0, v0.x, a0); a1 = fmaf(w0, v0.y, a1);
            a2 = fmaf(w0, v0.z, a2); a3 = fmaf(w0, v0.w, a3);
            a0 = fmaf(w1, v1.x, a0); a1 = fmaf(w1, v1.y, a1);
            a2 = fmaf(w1, v1.z, a2); a3 = fmaf(w1, v1.w, a3);
            a0 = fmaf(w2, v2.x, a0); a1 = fmaf(w2, v2.y, a1);
            a2 = fmaf(w2, v2.z, a2); a3 = fmaf(w2, v2.w, a3);
            a0 = fmaf(w3, v3.x, a0); a1 = fmaf(w3, v3.y, a1);
            a2 = fmaf(w3, v3.z, a2); a3 = fmaf(w3, v3.w, a3);
        }
    }
    a0 += __shfl_xor(a0, 16); a1 += __shfl_xor(a1, 16);
    a2 += __shfl_xor(a2, 16); a3 += __shfl_xor(a3, 16);
    a0 += __shfl_xor(a0, 32); a1 += __shfl_xor(a1, 32);
    a2 += __shfl_xor(a2, 32); a3 += __shfl_xor(a3, 32);
    if (sub == 0) {
        float dn = dinv[node];
        float sc = SQOUT ? dn * dn : dn;
        *(float4*)(y + (size_t)node * 64 + fq * 4) =
            make_float4(sc * a0, sc * a1, sc * a2, sc * a3);
    }
}

// ---------------------------------------------------------------------------
// Fused tail (node-major Xs, conflict-free LDS).
// ---------------------------------------------------------------------------
__global__ __launch_bounds__(256) void k_final(const float* __restrict__ xt, const float* __restrict__ xy,
                                               const float* __restrict__ xc, const float* __restrict__ W1,
                                               const float* __restrict__ b1, const float* __restrict__ W2,
                                               const float* __restrict__ b2, float* __restrict__ out) {
    __shared__ float Xs[64][192];
    __shared__ float lg[64][3];
    const int tid = threadIdx.x;
    const int wave = tid >> 6, lane = tid & 63;
    const int nbase = blockIdx.x * 64;

    for (int g = 0; g < 16; ++g) {
        int m = g * 4 + wave;
        int node = nbase + m;
        float t = 0.f, y = 0.f, c = 0.f;
        if (node < NN) {
            int b = node * 64 + lane;
            t = xt[b]; y = xy[b]; c = xc[b];
        }
        float sst = t * t, ssy = y * y, ssc = c * c;
        #pragma unroll
        for (int off = 32; off > 0; off >>= 1) {
            sst += __shfl_xor(sst, off);
            ssy += __shfl_xor(ssy, off);
            ssc += __shfl_xor(ssc, off);
        }
        t /= fmaxf(sqrtf(sst), 1e-12f);
        y /= fmaxf(sqrtf(ssy), 1e-12f);
        c /= fmaxf(sqrtf(ssc), 1e-12f);
        Xs[m][lane]       = t;
        Xs[m][64 + lane]  = y;
        Xs[m][128 + lane] = c;
    }
    __syncthreads();

    const int cg = tid & 31;
    const int rg = tid >> 5;
    float acc[8][4];
    {
        float4 bv = *(const float4*)(b1 + cg * 4);
        #pragma unroll
        for (int i = 0; i < 8; ++i) {
            acc[i][0] = bv.x; acc[i][1] = bv.y; acc[i][2] = bv.z; acc[i][3] = bv.w;
        }
    }
    for (int kc = 0; kc < 192; kc += 4) {
        float4 xv[8];
        #pragma unroll
        for (int i = 0; i < 8; ++i) xv[i] = *(const float4*)&Xs[rg * 8 + i][kc];
        float4 w0 = *(const float4*)(W1 + (kc + 0) * 128 + cg * 4);
        float4 w1 = *(const float4*)(W1 + (kc + 1) * 128 + cg * 4);
        float4 w2 = *(const float4*)(W1 + (kc + 2) * 128 + cg * 4);
        float4 w3 = *(const float4*)(W1 + (kc + 3) * 128 + cg * 4);
        #pragma unroll
        for (int i = 0; i < 8; ++i) {
            float4 xi = xv[i];
            acc[i][0] = fmaf(xi.x, w0.x, acc[i][0]); acc[i][1] = fmaf(xi.x, w0.y, acc[i][1]);
            acc[i][2] = fmaf(xi.x, w0.z, acc[i][2]); acc[i][3] = fmaf(xi.x, w0.w, acc[i][3]);
            acc[i][0] = fmaf(xi.y, w1.x, acc[i][0]); acc[i][1] = fmaf(xi.y, w1.y, acc[i][1]);
            acc[i][2] = fmaf(xi.y, w1.z, acc[i][2]); acc[i][3] = fmaf(xi.y, w1.w, acc[i][3]);
            acc[i][0] = fmaf(xi.z, w2.x, acc[i][0]); acc[i][1] = fmaf(xi.z, w2.y, acc[i][1]);
            acc[i][2] = fmaf(xi.z, w2.z, acc[i][2]); acc[i][3] = fmaf(xi.z, w2.w, acc[i][3]);
            acc[i][0] = fmaf(xi.w, w3.x, acc[i][0]); acc[i][1] = fmaf(xi.w, w3.y, acc[i][1]);
            acc[i][2] = fmaf(xi.w, w3.z, acc[i][2]); acc[i][3] = fmaf(xi.w, w3.w, acc[i][3]);
        }
    }

    float w2c[4][3];
    #pragma unroll
    for (int j = 0; j < 4; ++j)
        #pragma unroll
        for (int q = 0; q < 3; ++q) w2c[j][q] = W2[(cg * 4 + j) * 3 + q];

    #pragma unroll
    for (int i = 0; i < 8; ++i) {
        float p0 = 0.f, p1 = 0.f, p2 = 0.f;
        #pragma unroll
        for (int j = 0; j < 4; ++j) {
            float h = fmaxf(acc[i][j], 0.f);
            p0 = fmaf(h, w2c[j][0], p0);
            p1 = fmaf(h, w2c[j][1], p1);
            p2 = fmaf(h, w2c[j][2], p2);
        }
        #pragma unroll
        for (int off = 16; off > 0; off >>= 1) {
            p0 += __shfl_xor(p0, off);
            p1 += __shfl_xor(p1, off);
            p2 += __shfl_xor(p2, off);
        }
        if (cg == 0) {
            lg[rg * 8 + i][0] = p0;
            lg[rg * 8 + i][1] = p1;
            lg[rg * 8 + i][2] = p2;
        }
    }
    __syncthreads();

    for (int g = 0; g < 16; ++g) {
        int m = g * 4 + wave;
        int node = nbase + m;
        if (node < NN) {
            float l0 = lg[m][0] + b2[0];
            float l1 = lg[m][1] + b2[1];
            float l2 = lg[m][2] + b2[2];
            float mx = fmaxf(l0, fmaxf(l1, l2));
            float e0 = __expf(l0 - mx), e1 = __expf(l1 - mx), e2 = __expf(l2 - mx);
            float inv = 1.0f / (e0 + e1 + e2);
            float t = Xs[m][lane], y = Xs[m][64 + lane], c = Xs[m][128 + lane];
            out[node * 64 + lane] = (e0 * t + e1 * y + e2 * c) * inv;
        }
    }
}

// ---------------------------------------------------------------------------
extern "C" void kernel_launch(void* const* d_in, const int* in_sizes, int n_in,
                              void* d_out, int out_size, void* d_ws, size_t ws_size,
                              hipStream_t stream) {
    const float* init_feat = (const float*)d_in[0];
    const float* W1 = (const float*)d_in[1];
    const float* b1 = (const float*)d_in[2];
    const float* W2 = (const float*)d_in[3];
    const float* b2 = (const float*)d_in[4];
    const int* ei[3] = {(const int*)d_in[5], (const int*)d_in[6], (const int*)d_in[7]}; // title, year, cat

    float* TMP = (float*)d_out;   // d_out doubles as a temp (fully rewritten before reads)

    float* B1 = (float*)d_ws;                     // [N*64]
    float* B2 = B1 + (size_t)NN * 64;             // [N*64]
    float* dinvA = B2 + (size_t)NN * 64;          // [3*N]
    int* cntA = (int*)(dinvA + 3 * NN);           // [3*N]
    int* rowA = cntA + 3 * NN;                    // [3*N]
    int* gpackedA = rowA + 3 * NN;                // [3*E]
    int* csrA = gpackedA + (size_t)3 * NE;        // [3*E]
    int* btotA = csrA + (size_t)3 * NE;           // [3*NB]
    int* bstartA = btotA + 3 * NB;                // [3*NB]
    int* gcurA = bstartA + 3 * NB;                // [3*NB]

    const int TB = 256;
    const int finalGrid = (NN + 63) / 64;

    hipMemsetAsync(btotA, 0, (size_t)(3 * NB) * sizeof(int), stream);

    k_bhist<<<3 * NCHUNK, TB, 0, stream>>>(ei[0], ei[1], ei[2], btotA);
    k_bscan2<<<1, TB, 0, stream>>>(btotA, bstartA, gcurA);
    k_bscat<<<3 * NCHUNK, TB, 0, stream>>>(ei[0], ei[1], ei[2], gcurA, gpackedA);
    k_bfin<<<3 * NB, TB, 0, stream>>>(gpackedA, bstartA, gcurA, cntA, dinvA, rowA, csrA);

    // convs: PRE = input pre-scaled by dinv, SQOUT = emit dinv^2-scaled output
    #define CONV(PRE, SQ, xp, yp, s) \
        k_gather<PRE, SQ><<<NN / 4, TB, 0, stream>>>((xp), (yp), csrA + (size_t)(s) * NE, \
                                                     rowA + (s) * NN, cntA + (s) * NN, dinvA + (s) * NN)
    // cat chain (set 2): init -> B1 -> B2 -> TMP
    CONV(false, true,  init_feat, B1, 2);
    CONV(true,  true,  B1,        B2, 2);
    CONV(true,  false, B2,        TMP, 2);
    // title chain (set 0): init -> B1 -> B2
    CONV(false, true,  init_feat, B1, 0);
    CONV(true,  false, B1,        B2, 0);
    // year (set 1): init -> B1
    CONV(false, false, init_feat, B1, 1);
    #undef CONV

    // xt=title(B2), xy=year(B1), xc=cat(TMP); writes d_out (row-local alias safe)
    k_final<<<finalGrid, TB, 0, stream>>>(B2, B1, TMP, W1, b1, W2, b2, TMP);
}

// Round 7
// 453.038 us; speedup vs baseline: 7.7787x; 1.0929x over previous
//
#include <hip/hip_runtime.h>

// PDA_GNN: 3-branch LightGCN. Bucket-multisplit CSR build; latency-pipelined
// register-accum gather convs; MFMA-based fused normalize/concat/MLP/softmax.
// N=100000, E=1250000, D=64.

constexpr int NN = 100000;
constexpr int NE = 1250000;
constexpr int BROWS = 128;                       // dst nodes per bucket
constexpr int NB = (NN + BROWS - 1) / BROWS;     // 782 buckets
constexpr int CHUNK = 8192;                      // edges per partition block
constexpr int NCHUNK = (NE + CHUNK - 1) / CHUNK; // 153

typedef short bf16x8 __attribute__((ext_vector_type(8)));
typedef short bf16x4 __attribute__((ext_vector_type(4)));
typedef float f32x4 __attribute__((ext_vector_type(4)));

__device__ inline short f2bf(float f) {          // f32 -> bf16 RNE
    unsigned u = __builtin_bit_cast(unsigned, f);
    u += 0x7FFFu + ((u >> 16) & 1u);
    return (short)(u >> 16);
}

// ---------------------------------------------------------------------------
// Per-chunk bucket histogram -> btot (few clustered global atomics)
// ---------------------------------------------------------------------------
__global__ __launch_bounds__(256) void k_bhist(const int* __restrict__ e0, const int* __restrict__ e1,
                                               const int* __restrict__ e2, int* __restrict__ btot) {
    __shared__ int hist[NB];
    const int tid = threadIdx.x;
    const int set = blockIdx.x / NCHUNK;
    const int chunk = blockIdx.x % NCHUNK;
    const int* ei = (set == 0) ? e0 : (set == 1) ? e1 : e2;
    const int ebase = chunk * CHUNK;
    for (int b = tid; b < NB; b += 256) hist[b] = 0;
    __syncthreads();
    #pragma unroll
    for (int j = 0; j < CHUNK / 256; ++j) {
        int e = ebase + tid + j * 256;
        if (e < NE) atomicAdd(&hist[ei[NE + e] >> 7], 1);
    }
    __syncthreads();
    for (int b = tid; b < NB; b += 256) {
        int h = hist[b];
        if (h > 0) atomicAdd(&btot[set * NB + b], h);
    }
}

// ---------------------------------------------------------------------------
// Scan bucket totals -> bstart, gcur (single block)
// ---------------------------------------------------------------------------
__global__ __launch_bounds__(256) void k_bscan2(const int* __restrict__ btot,
                                                int* __restrict__ bstart, int* __restrict__ gcur) {
    const int tid = threadIdx.x;
    if (tid >= 64) return;
    for (int s = 0; s < 3; ++s) {
        int run = 0;
        for (int base = 0; base < NB; base += 64) {
            int idx = base + tid;
            int v = (idx < NB) ? btot[s * NB + idx] : 0;
            int incl = v;
            #pragma unroll
            for (int off = 1; off < 64; off <<= 1) {
                int u = __shfl_up(incl, off);
                if (tid >= off) incl += u;
            }
            if (idx < NB) {
                int st = run + incl - v;
                bstart[s * NB + idx] = st;
                gcur[s * NB + idx] = st;
            }
            run += __shfl(incl, 63);
        }
    }
}

// ---------------------------------------------------------------------------
// Bucket multisplit: LDS-stage 8192 edges, LDS histogram, one global atomic
// per (chunk,bucket), write packed (dlow<<17 | src) in ~contiguous runs.
// ---------------------------------------------------------------------------
__global__ __launch_bounds__(256) void k_bscat(const int* __restrict__ e0, const int* __restrict__ e1,
                                               const int* __restrict__ e2,
                                               int* __restrict__ gcur, int* __restrict__ gpacked) {
    __shared__ int lpack[CHUNK];
    __shared__ unsigned short lbkt[CHUNK];
    __shared__ int hist[NB];
    __shared__ int lbase[NB];
    __shared__ int lcur[NB];
    const int tid = threadIdx.x;
    const int set = blockIdx.x / NCHUNK;
    const int chunk = blockIdx.x % NCHUNK;
    const int* ei = (set == 0) ? e0 : (set == 1) ? e1 : e2;
    const int ebase = chunk * CHUNK;

    for (int b = tid; b < NB; b += 256) { hist[b] = 0; lcur[b] = 0; }
    __syncthreads();

    #pragma unroll
    for (int j = 0; j < CHUNK / 256; ++j) {
        int k = tid + j * 256;
        int e = ebase + k;
        if (e < NE) {
            int s = ei[e];
            int d = ei[NE + e];
            int b = d >> 7;
            lpack[k] = ((d & 127) << 17) | s;
            lbkt[k] = (unsigned short)b;
            atomicAdd(&hist[b], 1);
        } else {
            lbkt[k] = 0xFFFFu;
        }
    }
    __syncthreads();
    for (int b = tid; b < NB; b += 256) {
        int h = hist[b];
        if (h > 0) lbase[b] = atomicAdd(&gcur[set * NB + b], h);
    }
    __syncthreads();
    int* gp = gpacked + (size_t)set * NE;
    #pragma unroll
    for (int j = 0; j < CHUNK / 256; ++j) {
        int k = tid + j * 256;
        unsigned short b = lbkt[k];
        if (b != 0xFFFFu) {
            int pos = lbase[b] + atomicAdd(&lcur[b], 1);
            gp[pos] = lpack[k];
        }
    }
}

// ---------------------------------------------------------------------------
// Per-bucket finalize: LDS histogram of the bucket window -> per-node cnt /
// dinv / rowstart (coalesced writes) + scatter window into per-row CSR.
// ---------------------------------------------------------------------------
__global__ __launch_bounds__(256) void k_bfin(const int* __restrict__ gpacked,
                                              const int* __restrict__ bstart,
                                              const int* __restrict__ gcur,   // end cursors
                                              int* __restrict__ cnt, float* __restrict__ dinv,
                                              int* __restrict__ rowstart, int* __restrict__ csr) {
    __shared__ int hist[BROWS];
    __shared__ int rst[BROWS];    // absolute csr start per row
    __shared__ int lcur[BROWS];
    const int tid = threadIdx.x;
    const int set = blockIdx.x / NB, b = blockIdx.x % NB;
    if (tid < BROWS) { hist[tid] = 0; lcur[tid] = 0; }
    __syncthreads();

    const int base = bstart[set * NB + b];
    const int n = gcur[set * NB + b] - base;
    const int* gp = gpacked + (size_t)set * NE + base;

    for (int k = tid; k < n; k += 256) atomicAdd(&hist[(gp[k] >> 17) & 127], 1);
    __syncthreads();

    if (tid < 64) {
        int v0 = hist[tid], v1 = hist[64 + tid];
        int i0 = v0;
        #pragma unroll
        for (int off = 1; off < 64; off <<= 1) {
            int u = __shfl_up(i0, off);
            if (tid >= off) i0 += u;
        }
        int t0 = __shfl(i0, 63);
        int i1 = v1;
        #pragma unroll
        for (int off = 1; off < 64; off <<= 1) {
            int u = __shfl_up(i1, off);
            if (tid >= off) i1 += u;
        }
        rst[tid] = base + i0 - v0;
        rst[64 + tid] = base + t0 + i1 - v1;
    }
    __syncthreads();

    if (tid < BROWS) {
        int node = b * BROWS + tid;
        if (node < NN) {
            int c = hist[tid];
            cnt[set * NN + node] = c;
            dinv[set * NN + node] = (c > 0) ? (1.0f / sqrtf((float)c)) : 0.0f;
            rowstart[set * NN + node] = rst[tid];
        }
    }

    int* cs = csr + (size_t)set * NE;
    for (int k = tid; k < n; k += 256) {
        int p = gp[k];
        int d = (p >> 17) & 127;
        int pos = rst[d] + atomicAdd(&lcur[d], 1);
        cs[pos] = p & 0x1FFFF;
    }
}

// ---------------------------------------------------------------------------
// W1 [192][128] f32 -> W1t [128][192] bf16 (B-fragment friendly)
// ---------------------------------------------------------------------------
__global__ __launch_bounds__(256) void k_prep(const float* __restrict__ W1, short* __restrict__ W1t) {
    int idx = blockIdx.x * 256 + threadIdx.x;
    if (idx < 128 * 192) {
        int n = idx & 127, k = idx >> 7;
        W1t[n * 192 + k] = f2bf(W1[k * 128 + n]);
    }
}

// ---------------------------------------------------------------------------
// LGConv gather, 4-deep pipelined: one wave per dst node, 16 lanes per edge
// (float4 each). Register accumulation + shfl combine. PRE: input already
// carries dinv[src]; SQOUT: emit dinv^2-scaled output for the chained conv.
// ---------------------------------------------------------------------------
template<bool PRE, bool SQOUT>
__global__ __launch_bounds__(256) void k_gather(const float* __restrict__ x, float* __restrict__ y,
                                                const int* __restrict__ csr, const int* __restrict__ rowstart,
                                                const int* __restrict__ cnt, const float* __restrict__ dinv) {
    const int node = blockIdx.x * 4 + (threadIdx.x >> 6);
    const int lane = threadIdx.x & 63;
    const int sub = lane >> 4;
    const int fq = lane & 15;
    const int n = cnt[node];
    float a0 = 0.f, a1 = 0.f, a2 = 0.f, a3 = 0.f;
    if (n > 0) {
        const int* lst = csr + rowstart[node];
        for (int i = sub; i < n; i += 16) {
            const int j1 = i + 4, j2 = i + 8, j3 = i + 12;
            const int s0 = lst[i];
            const int s1 = lst[j1 < n ? j1 : n - 1];
            const int s2 = lst[j2 < n ? j2 : n - 1];
            const int s3 = lst[j3 < n ? j3 : n - 1];
            float w0, w1, w2, w3;
            if (PRE) {
                w0 = 1.f;
                w1 = (j1 < n) ? 1.f : 0.f;
                w2 = (j2 < n) ? 1.f : 0.f;
                w3 = (j3 < n) ? 1.f : 0.f;
            } else {
                w0 = dinv[s0];
                w1 = (j1 < n) ? dinv[s1] : 0.f;
                w2 = (j2 < n) ? dinv[s2] : 0.f;
                w3 = (j3 < n) ? dinv[s3] : 0.f;
            }
            const float4 v0 = *(const float4*)(x + (size_t)s0 * 64 + fq * 4);
            const float4 v1 = *(const float4*)(x + (size_t)s1 * 64 + fq * 4);
            const float4 v2 = *(const float4*)(x + (size_t)s2 * 64 + fq * 4);
            const float4 v3 = *(const float4*)(x + (size_t)s3 * 64 + fq * 4);
            a0 = fmaf(w0, v0.x, a0); a1 = fmaf(w0, v0.y, a1);
            a2 = fmaf(w0, v0.z, a2); a3 = fmaf(w0, v0.w, a3);
            a0 = fmaf(w1, v1.x, a0); a1 = fmaf(w1, v1.y, a1);
            a2 = fmaf(w1, v1.z, a2); a3 = fmaf(w1, v1.w, a3);
            a0 = fmaf(w2, v2.x, a0); a1 = fmaf(w2, v2.y, a1);
            a2 = fmaf(w2, v2.z, a2); a3 = fmaf(w2, v2.w, a3);
            a0 = fmaf(w3, v3.x, a0); a1 = fmaf(w3, v3.y, a1);
            a2 = fmaf(w3, v3.z, a2); a3 = fmaf(w3, v3.w, a3);
        }
    }
    a0 += __shfl_xor(a0, 16); a1 += __shfl_xor(a1, 16);
    a2 += __shfl_xor(a2, 16); a3 += __shfl_xor(a3, 16);
    a0 += __shfl_xor(a0, 32); a1 += __shfl_xor(a1, 32);
    a2 += __shfl_xor(a2, 32); a3 += __shfl_xor(a3, 32);
    if (sub == 0) {
        float dn = dinv[node];
        float sc = SQOUT ? dn * dn : dn;
        *(float4*)(y + (size_t)node * 64 + fq * 4) =
            make_float4(sc * a0, sc * a1, sc * a2, sc * a3);
    }
}

// ---------------------------------------------------------------------------
// Fused tail, MFMA version. 64 nodes/block, 4 waves.
// Phase 1: normalize -> bf16 Xn[64][200] LDS (+1/norms).
// Phase 2: H=relu(Xn@W1+b1) via 16x16x32 bf16 MFMA (wave = 16-node strip),
//          logits = relu(H)@W2 + b2, softmax -> per-node weights in LDS.
// Phase 3: out = sum_q att_q*rnorm_q*x_q (raw f32 re-read, L2-hot).
// A/B fragments use a consistent (group,reg)->k bijection; D layout is the
// HW-verified col=lane&15, row=(lane>>4)*4+reg.
// ---------------------------------------------------------------------------
constexpr int XROW = 200;   // bf16 per Xn row (192 + 8 pad: 400 B -> bank-friendly)

__global__ __launch_bounds__(256) void k_final(const float* __restrict__ xt, const float* __restrict__ xy,
                                               const float* __restrict__ xc, const short* __restrict__ W1t,
                                               const float* __restrict__ b1, const float* __restrict__ W2,
                                               const float* __restrict__ b2, float* __restrict__ out) {
    __shared__ alignas(16) short Xn[64 * XROW];   // 25600 B
    __shared__ float rnorm[3 * 64];
    __shared__ float attw[64][4];
    const int tid = threadIdx.x;
    const int wid = tid >> 6, lane = tid & 63;
    const int slot = lane >> 4, fq = lane & 15;
    const int m0 = wid * 16;
    const int nbase = blockIdx.x * 64;

    // ---- phase 1: per-(node,branch) row normalize, 4 rows per wave-iter
    #pragma unroll
    for (int it = 0; it < 12; ++it) {
        int idx = it * 4 + slot;              // 0..47 = branch*16 + noff
        int br = idx >> 4, noff = idx & 15;
        int m = m0 + noff;
        int nodeg = nbase + m;
        const float* xp = (br == 0) ? xt : (br == 1) ? xy : xc;
        float4 v = make_float4(0.f, 0.f, 0.f, 0.f);
        if (nodeg < NN) v = *(const float4*)(xp + (size_t)nodeg * 64 + fq * 4);
        float ss = v.x * v.x + v.y * v.y + v.z * v.z + v.w * v.w;
        #pragma unroll
        for (int off = 8; off > 0; off >>= 1) ss += __shfl_xor(ss, off);
        float rn = 1.0f / fmaxf(sqrtf(ss), 1e-12f);
        bf16x4 s4;
        s4[0] = f2bf(v.x * rn); s4[1] = f2bf(v.y * rn);
        s4[2] = f2bf(v.z * rn); s4[3] = f2bf(v.w * rn);
        *(bf16x4*)&Xn[m * XROW + br * 64 + fq * 4] = s4;
        if (fq == 0) rnorm[br * 64 + m] = rn;
    }
    __syncthreads();

    // ---- phase 2: MFMA GEMM + logits + softmax
    const int mrow = lane & 15, g = lane >> 4;
    bf16x8 afr[6];
    #pragma unroll
    for (int kk = 0; kk < 6; ++kk)
        afr[kk] = *(const bf16x8*)&Xn[(m0 + mrow) * XROW + kk * 32 + g * 8];
    f32x4 acc[8];
    #pragma unroll
    for (int nt = 0; nt < 8; ++nt) acc[nt] = (f32x4){0.f, 0.f, 0.f, 0.f};
    #pragma unroll
    for (int nt = 0; nt < 8; ++nt) {
        const short* wp = W1t + (nt * 16 + mrow) * 192 + g * 8;
        #pragma unroll
        for (int kk = 0; kk < 6; ++kk)
            acc[nt] = __builtin_amdgcn_mfma_f32_16x16x32_bf16(
                afr[kk], *(const bf16x8*)(wp + kk * 32), acc[nt], 0, 0, 0);
    }
    float p[4][3] = {};
    #pragma unroll
    for (int nt = 0; nt < 8; ++nt) {
        int col = nt * 16 + mrow;
        float b1v = b1[col];
        float w20 = W2[col * 3 + 0], w21 = W2[col * 3 + 1], w22 = W2[col * 3 + 2];
        #pragma unroll
        for (int i = 0; i < 4; ++i) {
            float h = fmaxf(acc[nt][i] + b1v, 0.f);
            p[i][0] = fmaf(h, w20, p[i][0]);
            p[i][1] = fmaf(h, w21, p[i][1]);
            p[i][2] = fmaf(h, w22, p[i][2]);
        }
    }
    #pragma unroll
    for (int i = 0; i < 4; ++i)
        #pragma unroll
        for (int off = 8; off > 0; off >>= 1) {
            p[i][0] += __shfl_xor(p[i][0], off);
            p[i][1] += __shfl_xor(p[i][1], off);
            p[i][2] += __shfl_xor(p[i][2], off);
        }
    if (mrow == 0) {
        #pragma unroll
        for (int i = 0; i < 4; ++i) {
            int m = m0 + g * 4 + i;
            float l0 = p[i][0] + b2[0], l1 = p[i][1] + b2[1], l2 = p[i][2] + b2[2];
            float mx = fmaxf(l0, fmaxf(l1, l2));
            float e0 = __expf(l0 - mx), e1 = __expf(l1 - mx), e2 = __expf(l2 - mx);
            float inv = 1.0f / (e0 + e1 + e2);
            attw[m][0] = e0 * inv * rnorm[m];
            attw[m][1] = e1 * inv * rnorm[64 + m];
            attw[m][2] = e2 * inv * rnorm[128 + m];
        }
    }
    __syncthreads();

    // ---- phase 3: weighted sum of raw rows (L2-hot re-read), coalesced out
    #pragma unroll
    for (int it = 0; it < 4; ++it) {
        int m = m0 + it * 4 + slot;
        int nodeg = nbase + m;
        if (nodeg < NN) {
            size_t base = (size_t)nodeg * 64 + fq * 4;
            float4 t = *(const float4*)(xt + base);
            float4 y = *(const float4*)(xy + base);
            float4 c = *(const float4*)(xc + base);
            float wt = attw[m][0], wy = attw[m][1], wc = attw[m][2];
            float4 o;
            o.x = wt * t.x + wy * y.x + wc * c.x;
            o.y = wt * t.y + wy * y.y + wc * c.y;
            o.z = wt * t.z + wy * y.z + wc * c.z;
            o.w = wt * t.w + wy * y.w + wc * c.w;
            *(float4*)(out + base) = o;
        }
    }
}

// ---------------------------------------------------------------------------
extern "C" void kernel_launch(void* const* d_in, const int* in_sizes, int n_in,
                              void* d_out, int out_size, void* d_ws, size_t ws_size,
                              hipStream_t stream) {
    const float* init_feat = (const float*)d_in[0];
    const float* W1 = (const float*)d_in[1];
    const float* b1 = (const float*)d_in[2];
    const float* W2 = (const float*)d_in[3];
    const float* b2 = (const float*)d_in[4];
    const int* ei[3] = {(const int*)d_in[5], (const int*)d_in[6], (const int*)d_in[7]}; // title, year, cat

    float* TMP = (float*)d_out;   // d_out doubles as a temp (fully rewritten before reads)

    float* B1 = (float*)d_ws;                     // [N*64]
    float* B2 = B1 + (size_t)NN * 64;             // [N*64]
    float* dinvA = B2 + (size_t)NN * 64;          // [3*N]
    int* cntA = (int*)(dinvA + 3 * NN);           // [3*N]
    int* rowA = cntA + 3 * NN;                    // [3*N]
    int* gpackedA = rowA + 3 * NN;                // [3*E]
    int* csrA = gpackedA + (size_t)3 * NE;        // [3*E]
    short* W1t = (short*)(csrA + (size_t)3 * NE); // [128*192] bf16 (16B-aligned offset)
    int* btotA = (int*)(W1t + 128 * 192);         // [3*NB]
    int* bstartA = btotA + 3 * NB;                // [3*NB]
    int* gcurA = bstartA + 3 * NB;                // [3*NB]

    const int TB = 256;
    const int finalGrid = (NN + 63) / 64;

    hipMemsetAsync(btotA, 0, (size_t)(3 * NB) * sizeof(int), stream);

    k_prep<<<(128 * 192 + TB - 1) / TB, TB, 0, stream>>>(W1, W1t);
    k_bhist<<<3 * NCHUNK, TB, 0, stream>>>(ei[0], ei[1], ei[2], btotA);
    k_bscan2<<<1, TB, 0, stream>>>(btotA, bstartA, gcurA);
    k_bscat<<<3 * NCHUNK, TB, 0, stream>>>(ei[0], ei[1], ei[2], gcurA, gpackedA);
    k_bfin<<<3 * NB, TB, 0, stream>>>(gpackedA, bstartA, gcurA, cntA, dinvA, rowA, csrA);

    // convs: PRE = input pre-scaled by dinv, SQOUT = emit dinv^2-scaled output
    #define CONV(PRE, SQ, xp, yp, s) \
        k_gather<PRE, SQ><<<NN / 4, TB, 0, stream>>>((xp), (yp), csrA + (size_t)(s) * NE, \
                                                     rowA + (s) * NN, cntA + (s) * NN, dinvA + (s) * NN)
    // cat chain (set 2): init -> B1 -> B2 -> TMP
    CONV(false, true,  init_feat, B1, 2);
    CONV(true,  true,  B1,        B2, 2);
    CONV(true,  false, B2,        TMP, 2);
    // title chain (set 0): init -> B1 -> B2
    CONV(false, true,  init_feat, B1, 0);
    CONV(true,  false, B1,        B2, 0);
    // year (set 1): init -> B1
    CONV(false, false, init_feat, B1, 1);
    #undef CONV

    // xt=title(B2), xy=year(B1), xc=cat(TMP); writes d_out (row-local alias safe)
    k_final<<<finalGrid, TB, 0, stream>>>(B2, B1, TMP, W1t, b1, W2, b2, TMP);
}

// Round 9
// 384.730 us; speedup vs baseline: 9.1598x; 1.1775x over previous
//
#include <hip/hip_runtime.h>

// PDA_GNN: 3-branch LightGCN, bf16 feature storage (f32 arithmetic).
// Padded-bucket CSR build (in-place), merged-round pipelined gathers,
// MFMA fused normalize/concat/MLP/softmax. N=100000, E=1250000, D=64.

constexpr int NN = 100000;
constexpr int NE = 1250000;
constexpr int BROWS = 128;                       // dst nodes per bucket
constexpr int NB = (NN + BROWS - 1) / BROWS;     // 782 buckets
constexpr int PADB = 2048;                       // per-bucket capacity (max ~1750)
constexpr int PADE = NB * PADB;                  // padded edges per set
constexpr int CHUNK = 8192;                      // edges per partition block
constexpr int NCHUNK = (NE + CHUNK - 1) / CHUNK; // 153
constexpr int XROW = 200;                        // bf16 per Xn row (192+8 pad)

typedef short bf16x8 __attribute__((ext_vector_type(8)));
typedef float f32x4 __attribute__((ext_vector_type(4)));

__device__ inline short f2bf(float f) {          // f32 -> bf16 RNE
    unsigned u = __builtin_bit_cast(unsigned, f);
    u += 0x7FFFu + ((u >> 16) & 1u);
    return (short)(u >> 16);
}
__device__ inline unsigned packbf(float a, float b) {
    return (unsigned)(unsigned short)f2bf(a) | ((unsigned)(unsigned short)f2bf(b) << 16);
}
__device__ inline float bflo(unsigned q) { return __builtin_bit_cast(float, q << 16); }
__device__ inline float bfhi(unsigned q) { return __builtin_bit_cast(float, q & 0xFFFF0000u); }

__device__ inline void edge_acc(float* acc, uint4 v, float w) {
    acc[0] = fmaf(w, bflo(v.x), acc[0]); acc[1] = fmaf(w, bfhi(v.x), acc[1]);
    acc[2] = fmaf(w, bflo(v.y), acc[2]); acc[3] = fmaf(w, bfhi(v.y), acc[3]);
    acc[4] = fmaf(w, bflo(v.z), acc[4]); acc[5] = fmaf(w, bfhi(v.z), acc[5]);
    acc[6] = fmaf(w, bflo(v.w), acc[6]); acc[7] = fmaf(w, bfhi(v.w), acc[7]);
}

// ---------------------------------------------------------------------------
// init_feat f32 -> bf16 rows
// ---------------------------------------------------------------------------
__global__ __launch_bounds__(256) void k_tobf(const float* __restrict__ x, unsigned short* __restrict__ o) {
    int i = blockIdx.x * 256 + threadIdx.x;      // one float4 per thread
    if (i < NN * 16) {
        float4 v = ((const float4*)x)[i];
        uint2 r;
        r.x = packbf(v.x, v.y);
        r.y = packbf(v.z, v.w);
        ((uint2*)o)[i] = r;
    }
}

// W1 [192][128] f32 -> W1t [128][192] bf16
__global__ __launch_bounds__(256) void k_prep(const float* __restrict__ W1, short* __restrict__ W1t) {
    int idx = blockIdx.x * 256 + threadIdx.x;
    if (idx < 128 * 192) {
        int n = idx & 127, k = idx >> 7;
        W1t[n * 192 + k] = f2bf(W1[k * 128 + n]);
    }
}

// gcur[s*NB+b] = b*PADB  (padded bucket bases)
__global__ __launch_bounds__(256) void k_ginit(int* __restrict__ gcur) {
    int i = blockIdx.x * 256 + threadIdx.x;
    if (i < 3 * NB) gcur[i] = (i % NB) * PADB;
}

// ---------------------------------------------------------------------------
// Bucket multisplit into padded regions: LDS-stage 8192 edges, LDS histogram,
// one global atomic per (chunk,bucket), write packed (dlow<<17 | src).
// ---------------------------------------------------------------------------
__global__ __launch_bounds__(256) void k_bscat(const int* __restrict__ e0, const int* __restrict__ e1,
                                               const int* __restrict__ e2,
                                               int* __restrict__ gcur, int* __restrict__ gpacked) {
    __shared__ int lpack[CHUNK];
    __shared__ unsigned short lbkt[CHUNK];
    __shared__ int hist[NB];
    __shared__ int lbase[NB];
    __shared__ int lcur[NB];
    const int tid = threadIdx.x;
    const int set = blockIdx.x / NCHUNK;
    const int chunk = blockIdx.x % NCHUNK;
    const int* ei = (set == 0) ? e0 : (set == 1) ? e1 : e2;
    const int ebase = chunk * CHUNK;

    for (int b = tid; b < NB; b += 256) { hist[b] = 0; lcur[b] = 0; }
    __syncthreads();

    #pragma unroll
    for (int j = 0; j < CHUNK / 256; ++j) {
        int k = tid + j * 256;
        int e = ebase + k;
        if (e < NE) {
            int s = ei[e];
            int d = ei[NE + e];
            int b = d >> 7;
            lpack[k] = ((d & 127) << 17) | s;
            lbkt[k] = (unsigned short)b;
            atomicAdd(&hist[b], 1);
        } else {
            lbkt[k] = 0xFFFFu;
        }
    }
    __syncthreads();
    for (int b = tid; b < NB; b += 256) {
        int h = hist[b];
        if (h > 0) lbase[b] = atomicAdd(&gcur[set * NB + b], h);
    }
    __syncthreads();
    int* gp = gpacked + (size_t)set * PADE;
    #pragma unroll
    for (int j = 0; j < CHUNK / 256; ++j) {
        int k = tid + j * 256;
        unsigned short b = lbkt[k];
        if (b != 0xFFFFu) {
            int pos = lbase[b] + atomicAdd(&lcur[b], 1);
            gp[pos] = lpack[k];
        }
    }
}

// ---------------------------------------------------------------------------
// Per-bucket finalize: stage window in LDS -> per-node cnt/dinv/rowstart
// (coalesced) + in-place rewrite of the window as per-row CSR (src only).
// ---------------------------------------------------------------------------
__global__ __launch_bounds__(256) void k_bfin(int* __restrict__ gpacked, const int* __restrict__ gcur,
                                              int* __restrict__ cnt, float* __restrict__ dinv,
                                              int* __restrict__ rowstart) {
    __shared__ int win[PADB];
    __shared__ int hist[BROWS];
    __shared__ int rst[BROWS];    // prefix within bucket (relative)
    __shared__ int lcur[BROWS];
    const int tid = threadIdx.x;
    const int set = blockIdx.x / NB, b = blockIdx.x % NB;
    if (tid < BROWS) { hist[tid] = 0; lcur[tid] = 0; }
    __syncthreads();

    const int base = b * PADB;
    const int n = gcur[set * NB + b] - base;
    int* gp = gpacked + (size_t)set * PADE + base;

    for (int k = tid; k < n; k += 256) {
        int p = gp[k];
        win[k] = p;
        atomicAdd(&hist[(p >> 17) & 127], 1);
    }
    __syncthreads();

    if (tid < 64) {
        int v0 = hist[tid], v1 = hist[64 + tid];
        int i0 = v0;
        #pragma unroll
        for (int off = 1; off < 64; off <<= 1) {
            int u = __shfl_up(i0, off);
            if (tid >= off) i0 += u;
        }
        int t0 = __shfl(i0, 63);
        int i1 = v1;
        #pragma unroll
        for (int off = 1; off < 64; off <<= 1) {
            int u = __shfl_up(i1, off);
            if (tid >= off) i1 += u;
        }
        rst[tid] = i0 - v0;
        rst[64 + tid] = t0 + i1 - v1;
    }
    __syncthreads();

    if (tid < BROWS) {
        int node = b * BROWS + tid;
        if (node < NN) {
            int c = hist[tid];
            cnt[set * NN + node] = c;
            dinv[set * NN + node] = (c > 0) ? (1.0f / sqrtf((float)c)) : 0.0f;
            rowstart[set * NN + node] = base + rst[tid];
        }
    }

    for (int k = tid; k < n; k += 256) {
        int p = win[k];
        int d = (p >> 17) & 127;
        int pos = rst[d] + atomicAdd(&lcur[d], 1);
        gp[pos] = p & 0x1FFFF;
    }
}

// ---------------------------------------------------------------------------
// Merged LGConv gather (bf16 rows): one wave per dst node, 8 lanes per edge
// (uint4 = 8 bf16), 2-deep unroll -> 16 rows in flight/wave. f32 accumulate,
// 3-round shfl combine. pre: skip dinv[src] (input pre-scaled); sq: emit
// dinv^2-scaled output for the chained conv.
// ---------------------------------------------------------------------------
struct GA {
    const unsigned short* x;
    unsigned short* y;
    const int* csr;
    const int* row;
    const int* cnt;
    const float* dinv;
    int pre, sq;
};

__global__ __launch_bounds__(256) void k_gather3(GA g0, GA g1, GA g2, int perset) {
    const int bset = blockIdx.x / perset;
    const int blk = blockIdx.x - bset * perset;
    const GA ga = (bset == 0) ? g0 : (bset == 1) ? g1 : g2;
    const int node = blk * 4 + (threadIdx.x >> 6);
    const int lane = threadIdx.x & 63;
    const int slot = lane >> 3, fo = lane & 7;
    const int n = ga.cnt[node];
    float acc[8] = {0.f, 0.f, 0.f, 0.f, 0.f, 0.f, 0.f, 0.f};

    if (n > 0) {
        const int* lst = ga.csr + ga.row[node];
        const bool pre = (ga.pre != 0);
        int i = slot;
        for (; i + 8 < n; i += 16) {
            int s0 = lst[i], s1 = lst[i + 8];
            float w0 = pre ? 1.f : ga.dinv[s0];
            float w1 = pre ? 1.f : ga.dinv[s1];
            uint4 v0 = *(const uint4*)(ga.x + (size_t)s0 * 64 + fo * 8);
            uint4 v1 = *(const uint4*)(ga.x + (size_t)s1 * 64 + fo * 8);
            edge_acc(acc, v0, w0);
            edge_acc(acc, v1, w1);
        }
        if (i < n) {
            int s = lst[i];
            float w = pre ? 1.f : ga.dinv[s];
            uint4 v = *(const uint4*)(ga.x + (size_t)s * 64 + fo * 8);
            edge_acc(acc, v, w);
        }
    }

    #pragma unroll
    for (int off = 8; off < 64; off <<= 1) {
        #pragma unroll
        for (int j = 0; j < 8; ++j) acc[j] += __shfl_xor(acc[j], off);
    }
    if (slot == 0) {
        float dn = ga.dinv[node];
        float sc = ga.sq ? dn * dn : dn;
        uint4 r;
        r.x = packbf(sc * acc[0], sc * acc[1]);
        r.y = packbf(sc * acc[2], sc * acc[3]);
        r.z = packbf(sc * acc[4], sc * acc[5]);
        r.w = packbf(sc * acc[6], sc * acc[7]);
        *(uint4*)(ga.y + (size_t)node * 64 + fo * 8) = r;
    }
}

// ---------------------------------------------------------------------------
// Fused tail, MFMA version, bf16 inputs. 64 nodes/block, 4 waves.
// Phase 1: normalize (8-lane slots) -> bf16 Xn[64][200] LDS + 1/norms.
// Phase 2: H=relu(Xn@W1+b1) via 16x16x32 bf16 MFMA, logits, softmax -> attw.
// Phase 3: out = sum_q attw_q * raw_q (bf16 re-read, f32 out).
// ---------------------------------------------------------------------------
__global__ __launch_bounds__(256) void k_final(const unsigned short* __restrict__ xt,
                                               const unsigned short* __restrict__ xy,
                                               const unsigned short* __restrict__ xc,
                                               const short* __restrict__ W1t,
                                               const float* __restrict__ b1,
                                               const float* __restrict__ W2,
                                               const float* __restrict__ b2,
                                               float* __restrict__ out) {
    __shared__ alignas(16) short Xn[64 * XROW];   // 25600 B
    __shared__ float rnorm[3 * 64];
    __shared__ float attw[64][4];
    const int tid = threadIdx.x;
    const int wid = tid >> 6, lane = tid & 63;
    const int slot = lane >> 3, fo = lane & 7;
    const int m0 = wid * 16;
    const int nbase = blockIdx.x * 64;

    // ---- phase 1: 48 rows per wave (16 nodes x 3 branches), 8-lane slots
    #pragma unroll
    for (int it = 0; it < 6; ++it) {
        int idx = it * 8 + slot;              // 0..47 = branch*16 + noff
        int br = idx >> 4, noff = idx & 15;
        int m = m0 + noff;
        int nodeg = nbase + m;
        const unsigned short* xp = (br == 0) ? xt : (br == 1) ? xy : xc;
        float f[8] = {0.f, 0.f, 0.f, 0.f, 0.f, 0.f, 0.f, 0.f};
        if (nodeg < NN) {
            uint4 v = *(const uint4*)(xp + (size_t)nodeg * 64 + fo * 8);
            f[0] = bflo(v.x); f[1] = bfhi(v.x); f[2] = bflo(v.y); f[3] = bfhi(v.y);
            f[4] = bflo(v.z); f[5] = bfhi(v.z); f[6] = bflo(v.w); f[7] = bfhi(v.w);
        }
        float ss = 0.f;
        #pragma unroll
        for (int j = 0; j < 8; ++j) ss = fmaf(f[j], f[j], ss);
        #pragma unroll
        for (int off = 1; off < 8; off <<= 1) ss += __shfl_xor(ss, off);
        float rn = 1.0f / fmaxf(sqrtf(ss), 1e-12f);
        uint4 r;
        r.x = packbf(f[0] * rn, f[1] * rn);
        r.y = packbf(f[2] * rn, f[3] * rn);
        r.z = packbf(f[4] * rn, f[5] * rn);
        r.w = packbf(f[6] * rn, f[7] * rn);
        *(uint4*)&Xn[m * XROW + br * 64 + fo * 8] = r;
        if (fo == 0) rnorm[br * 64 + m] = rn;
    }
    __syncthreads();

    // ---- phase 2: MFMA GEMM + logits + softmax
    const int mrow = lane & 15, g = lane >> 4;
    bf16x8 afr[6];
    #pragma unroll
    for (int kk = 0; kk < 6; ++kk)
        afr[kk] = *(const bf16x8*)&Xn[(m0 + mrow) * XROW + kk * 32 + g * 8];
    f32x4 acc[8];
    #pragma unroll
    for (int nt = 0; nt < 8; ++nt) acc[nt] = (f32x4){0.f, 0.f, 0.f, 0.f};
    #pragma unroll
    for (int nt = 0; nt < 8; ++nt) {
        const short* wp = W1t + (nt * 16 + mrow) * 192 + g * 8;
        #pragma unroll
        for (int kk = 0; kk < 6; ++kk)
            acc[nt] = __builtin_amdgcn_mfma_f32_16x16x32_bf16(
                afr[kk], *(const bf16x8*)(wp + kk * 32), acc[nt], 0, 0, 0);
    }
    float p[4][3] = {};
    #pragma unroll
    for (int nt = 0; nt < 8; ++nt) {
        int col = nt * 16 + mrow;
        float b1v = b1[col];
        float w20 = W2[col * 3 + 0], w21 = W2[col * 3 + 1], w22 = W2[col * 3 + 2];
        #pragma unroll
        for (int i = 0; i < 4; ++i) {
            float h = fmaxf(acc[nt][i] + b1v, 0.f);
            p[i][0] = fmaf(h, w20, p[i][0]);
            p[i][1] = fmaf(h, w21, p[i][1]);
            p[i][2] = fmaf(h, w22, p[i][2]);
        }
    }
    #pragma unroll
    for (int i = 0; i < 4; ++i)
        #pragma unroll
        for (int off = 8; off > 0; off >>= 1) {
            p[i][0] += __shfl_xor(p[i][0], off);
            p[i][1] += __shfl_xor(p[i][1], off);
            p[i][2] += __shfl_xor(p[i][2], off);
        }
    if (mrow == 0) {
        #pragma unroll
        for (int i = 0; i < 4; ++i) {
            int m = m0 + g * 4 + i;
            float l0 = p[i][0] + b2[0], l1 = p[i][1] + b2[1], l2 = p[i][2] + b2[2];
            float mx = fmaxf(l0, fmaxf(l1, l2));
            float e0 = __expf(l0 - mx), e1 = __expf(l1 - mx), e2 = __expf(l2 - mx);
            float inv = 1.0f / (e0 + e1 + e2);
            attw[m][0] = e0 * inv * rnorm[m];
            attw[m][1] = e1 * inv * rnorm[64 + m];
            attw[m][2] = e2 * inv * rnorm[128 + m];
        }
    }
    __syncthreads();

    // ---- phase 3: weighted sum of raw bf16 rows, f32 coalesced out
    #pragma unroll
    for (int it = 0; it < 2; ++it) {
        int m = m0 + it * 8 + slot;
        int nodeg = nbase + m;
        if (nodeg < NN) {
            size_t base = (size_t)nodeg * 64 + fo * 8;
            uint4 tv = *(const uint4*)(xt + base);
            uint4 yv = *(const uint4*)(xy + base);
            uint4 cv = *(const uint4*)(xc + base);
            float wt = attw[m][0], wy = attw[m][1], wc = attw[m][2];
            float4 lo4, hi4;
            lo4.x = wt * bflo(tv.x) + wy * bflo(yv.x) + wc * bflo(cv.x);
            lo4.y = wt * bfhi(tv.x) + wy * bfhi(yv.x) + wc * bfhi(cv.x);
            lo4.z = wt * bflo(tv.y) + wy * bflo(yv.y) + wc * bflo(cv.y);
            lo4.w = wt * bfhi(tv.y) + wy * bfhi(yv.y) + wc * bfhi(cv.y);
            hi4.x = wt * bflo(tv.z) + wy * bflo(yv.z) + wc * bflo(cv.z);
            hi4.y = wt * bfhi(tv.z) + wy * bfhi(yv.z) + wc * bfhi(cv.z);
            hi4.z = wt * bflo(tv.w) + wy * bflo(yv.w) + wc * bflo(cv.w);
            hi4.w = wt * bfhi(tv.w) + wy * bfhi(yv.w) + wc * bfhi(cv.w);
            *(float4*)(out + base) = lo4;
            *(float4*)(out + base + 4) = hi4;
        }
    }
}

// ---------------------------------------------------------------------------
extern "C" void kernel_launch(void* const* d_in, const int* in_sizes, int n_in,
                              void* d_out, int out_size, void* d_ws, size_t ws_size,
                              hipStream_t stream) {
    const float* init_feat = (const float*)d_in[0];
    const float* W1 = (const float*)d_in[1];
    const float* b1 = (const float*)d_in[2];
    const float* W2 = (const float*)d_in[3];
    const float* b2 = (const float*)d_in[4];
    const int* ei[3] = {(const int*)d_in[5], (const int*)d_in[6], (const int*)d_in[7]}; // title, year, cat

    // workspace: 5 bf16 feature buffers + CSR structures (~87 MB)
    unsigned short* P0 = (unsigned short*)d_ws;        // initb, later cat2
    unsigned short* P1 = P0 + (size_t)NN * 64;         // cat1, later cat3
    unsigned short* P2 = P1 + (size_t)NN * 64;         // title1
    unsigned short* P3 = P2 + (size_t)NN * 64;         // year final
    unsigned short* P4 = P3 + (size_t)NN * 64;         // title final
    float* dinvA = (float*)(P4 + (size_t)NN * 64);     // [3*N]
    int* cntA = (int*)(dinvA + 3 * NN);                // [3*N]
    int* rowA = cntA + 3 * NN;                         // [3*N]
    int* gpackedA = rowA + 3 * NN;                     // [3*PADE] (CSR in-place)
    short* W1t = (short*)(gpackedA + (size_t)3 * PADE);// [128*192]
    int* gcurA = (int*)(W1t + 128 * 192);              // [3*NB]

    const int TB = 256;
    const int finalGrid = (NN + 63) / 64;

    k_tobf<<<(NN * 16 + TB - 1) / TB, TB, 0, stream>>>(init_feat, P0);
    k_prep<<<(128 * 192 + TB - 1) / TB, TB, 0, stream>>>(W1, W1t);
    k_ginit<<<(3 * NB + TB - 1) / TB, TB, 0, stream>>>(gcurA);
    k_bscat<<<3 * NCHUNK, TB, 0, stream>>>(ei[0], ei[1], ei[2], gcurA, gpackedA);
    k_bfin<<<3 * NB, TB, 0, stream>>>(gpackedA, gcurA, cntA, dinvA, rowA);

    #define MKGA(xp, yp, s, PRE, SQ) \
        GA{ (xp), (yp), gpackedA + (size_t)(s) * PADE, rowA + (s) * NN, \
            cntA + (s) * NN, dinvA + (s) * NN, (PRE), (SQ) }
    // Round A: cat1, title1, year1 (all read initb)
    {
        GA a0 = MKGA(P0, P1, 2, 0, 1);
        GA a1 = MKGA(P0, P2, 0, 0, 1);
        GA a2 = MKGA(P0, P3, 1, 0, 0);
        k_gather3<<<3 * (NN / 4), TB, 0, stream>>>(a0, a1, a2, NN / 4);
    }
    // Round B: cat2 (P1->P0), title2 (P2->P4)
    {
        GA b0 = MKGA(P1, P0, 2, 1, 1);
        GA b1g = MKGA(P2, P4, 0, 1, 0);
        k_gather3<<<2 * (NN / 4), TB, 0, stream>>>(b0, b1g, b1g, NN / 4);
    }
    // Round C: cat3 (P0->P1)
    {
        GA c0 = MKGA(P0, P1, 2, 1, 0);
        k_gather3<<<NN / 4, TB, 0, stream>>>(c0, c0, c0, NN / 4);
    }
    #undef MKGA

    // xt=title(P4), xy=year(P3), xc=cat(P1)
    k_final<<<finalGrid, TB, 0, stream>>>(P4, P3, P1, W1t, b1, W2, b2, (float*)d_out);
}

// Round 10
// 382.336 us; speedup vs baseline: 9.2172x; 1.0063x over previous
//
#include <hip/hip_runtime.h>

// PDA_GNN: 3-branch LightGCN, bf16 feature storage (f32 arithmetic).
// Pre-scaled inputs (all convs weight=1) + v_dot2_f32_bf16 accumulate.
// Padded-bucket CSR build (in-place), merged-round gathers, MFMA fused tail.
// N=100000, E=1250000, D=64.

constexpr int NN = 100000;
constexpr int NE = 1250000;
constexpr int BROWS = 128;                       // dst nodes per bucket
constexpr int NB = (NN + BROWS - 1) / BROWS;     // 782 buckets
constexpr int PADB = 2048;                       // per-bucket capacity (max ~1780)
constexpr int PADE = NB * PADB;                  // padded edges per set
constexpr int CHUNK = 8192;                      // edges per partition block
constexpr int NCHUNK = (NE + CHUNK - 1) / CHUNK; // 153
constexpr int XROW = 200;                        // bf16 per Xn row (192+8 pad)

typedef short bf16x8 __attribute__((ext_vector_type(8)));
typedef float f32x4 __attribute__((ext_vector_type(4)));

__device__ inline short f2bf(float f) {          // f32 -> bf16 RNE
    unsigned u = __builtin_bit_cast(unsigned, f);
    u += 0x7FFFu + ((u >> 16) & 1u);
    return (short)(u >> 16);
}
__device__ inline unsigned packbf(float a, float b) {
    return (unsigned)(unsigned short)f2bf(a) | ((unsigned)(unsigned short)f2bf(b) << 16);
}
__device__ inline float bflo(unsigned q) { return __builtin_bit_cast(float, q << 16); }
__device__ inline float bfhi(unsigned q) { return __builtin_bit_cast(float, q & 0xFFFF0000u); }

// v_dot2_f32_bf16: D = lo(a)*lo(b) + hi(a)*hi(b) + c   (f32 accumulate)
__device__ inline float dot2bf(unsigned a, unsigned b, float c) {
    float d;
    asm("v_dot2_f32_bf16 %0, %1, %2, %3" : "=v"(d) : "v"(a), "v"(b), "v"(c));
    return d;
}
constexpr unsigned SEL_LO = 0x00003F80u;   // bf16 pair (1.0, 0.0)
constexpr unsigned SEL_HI = 0x3F800000u;   // bf16 pair (0.0, 1.0)

__device__ inline void dotacc(float* acc, uint4 v, unsigned sl, unsigned sh) {
    acc[0] = dot2bf(v.x, sl, acc[0]); acc[1] = dot2bf(v.x, sh, acc[1]);
    acc[2] = dot2bf(v.y, sl, acc[2]); acc[3] = dot2bf(v.y, sh, acc[3]);
    acc[4] = dot2bf(v.z, sl, acc[4]); acc[5] = dot2bf(v.z, sh, acc[5]);
    acc[6] = dot2bf(v.w, sl, acc[6]); acc[7] = dot2bf(v.w, sh, acc[7]);
}

// ---------------------------------------------------------------------------
// W1 [192][128] f32 -> W1t [128][192] bf16
// ---------------------------------------------------------------------------
__global__ __launch_bounds__(256) void k_prep(const float* __restrict__ W1, short* __restrict__ W1t) {
    int idx = blockIdx.x * 256 + threadIdx.x;
    if (idx < 128 * 192) {
        int n = idx & 127, k = idx >> 7;
        W1t[n * 192 + k] = f2bf(W1[k * 128 + n]);
    }
}

// gcur[s*NB+b] = b*PADB  (padded bucket bases)
__global__ __launch_bounds__(256) void k_ginit(int* __restrict__ gcur) {
    int i = blockIdx.x * 256 + threadIdx.x;
    if (i < 3 * NB) gcur[i] = (i % NB) * PADB;
}

// ---------------------------------------------------------------------------
// Bucket multisplit into padded regions: LDS-stage 8192 edges, LDS histogram,
// one global atomic per (chunk,bucket), write packed (dlow<<17 | src).
// ---------------------------------------------------------------------------
__global__ __launch_bounds__(256) void k_bscat(const int* __restrict__ e0, const int* __restrict__ e1,
                                               const int* __restrict__ e2,
                                               int* __restrict__ gcur, int* __restrict__ gpacked) {
    __shared__ int lpack[CHUNK];
    __shared__ unsigned short lbkt[CHUNK];
    __shared__ int hist[NB];
    __shared__ int lbase[NB];
    __shared__ int lcur[NB];
    const int tid = threadIdx.x;
    const int set = blockIdx.x / NCHUNK;
    const int chunk = blockIdx.x % NCHUNK;
    const int* ei = (set == 0) ? e0 : (set == 1) ? e1 : e2;
    const int ebase = chunk * CHUNK;

    for (int b = tid; b < NB; b += 256) { hist[b] = 0; lcur[b] = 0; }
    __syncthreads();

    #pragma unroll
    for (int j = 0; j < CHUNK / 256; ++j) {
        int k = tid + j * 256;
        int e = ebase + k;
        if (e < NE) {
            int s = ei[e];
            int d = ei[NE + e];
            int b = d >> 7;
            lpack[k] = ((d & 127) << 17) | s;
            lbkt[k] = (unsigned short)b;
            atomicAdd(&hist[b], 1);
        } else {
            lbkt[k] = 0xFFFFu;
        }
    }
    __syncthreads();
    for (int b = tid; b < NB; b += 256) {
        int h = hist[b];
        if (h > 0) lbase[b] = atomicAdd(&gcur[set * NB + b], h);
    }
    __syncthreads();
    int* gp = gpacked + (size_t)set * PADE;
    #pragma unroll
    for (int j = 0; j < CHUNK / 256; ++j) {
        int k = tid + j * 256;
        unsigned short b = lbkt[k];
        if (b != 0xFFFFu) {
            int pos = lbase[b] + atomicAdd(&lcur[b], 1);
            gp[pos] = lpack[k];
        }
    }
}

// ---------------------------------------------------------------------------
// Per-bucket finalize: stage window in LDS -> per-node cnt/dinv/rowstart
// (coalesced) + in-place rewrite of the window as per-row CSR (src only).
// ---------------------------------------------------------------------------
__global__ __launch_bounds__(256) void k_bfin(int* __restrict__ gpacked, const int* __restrict__ gcur,
                                              int* __restrict__ cnt, float* __restrict__ dinv,
                                              int* __restrict__ rowstart) {
    __shared__ int win[PADB];
    __shared__ int hist[BROWS];
    __shared__ int rst[BROWS];    // prefix within bucket (relative)
    __shared__ int lcur[BROWS];
    const int tid = threadIdx.x;
    const int set = blockIdx.x / NB, b = blockIdx.x % NB;
    if (tid < BROWS) { hist[tid] = 0; lcur[tid] = 0; }
    __syncthreads();

    const int base = b * PADB;
    const int n = gcur[set * NB + b] - base;
    int* gp = gpacked + (size_t)set * PADE + base;

    for (int k = tid; k < n; k += 256) {
        int p = gp[k];
        win[k] = p;
        atomicAdd(&hist[(p >> 17) & 127], 1);
    }
    __syncthreads();

    if (tid < 64) {
        int v0 = hist[tid], v1 = hist[64 + tid];
        int i0 = v0;
        #pragma unroll
        for (int off = 1; off < 64; off <<= 1) {
            int u = __shfl_up(i0, off);
            if (tid >= off) i0 += u;
        }
        int t0 = __shfl(i0, 63);
        int i1 = v1;
        #pragma unroll
        for (int off = 1; off < 64; off <<= 1) {
            int u = __shfl_up(i1, off);
            if (tid >= off) i1 += u;
        }
        rst[tid] = i0 - v0;
        rst[64 + tid] = t0 + i1 - v1;
    }
    __syncthreads();

    if (tid < BROWS) {
        int node = b * BROWS + tid;
        if (node < NN) {
            int c = hist[tid];
            cnt[set * NN + node] = c;
            dinv[set * NN + node] = (c > 0) ? (1.0f / sqrtf((float)c)) : 0.0f;
            rowstart[set * NN + node] = base + rst[tid];
        }
    }

    for (int k = tid; k < n; k += 256) {
        int p = win[k];
        int d = (p >> 17) & 127;
        int pos = rst[d] + atomicAdd(&lcur[d], 1);
        gp[pos] = p & 0x1FFFF;
    }
}

// ---------------------------------------------------------------------------
// init f32 -> three bf16 copies scaled by the per-set dinv[node].
// Makes every conv's edge weight exactly 1.0.
// ---------------------------------------------------------------------------
__global__ __launch_bounds__(256) void k_scale3(const float* __restrict__ x, const float* __restrict__ dinv,
                                                unsigned short* __restrict__ ot,
                                                unsigned short* __restrict__ oy,
                                                unsigned short* __restrict__ oc) {
    int i = blockIdx.x * 256 + threadIdx.x;      // one float4 per thread
    if (i < NN * 16) {
        int node = i >> 4;
        float4 v = ((const float4*)x)[i];
        float dt = dinv[node], dy = dinv[NN + node], dc = dinv[2 * NN + node];
        uint2 rt, ry, rc;
        rt.x = packbf(v.x * dt, v.y * dt); rt.y = packbf(v.z * dt, v.w * dt);
        ry.x = packbf(v.x * dy, v.y * dy); ry.y = packbf(v.z * dy, v.w * dy);
        rc.x = packbf(v.x * dc, v.y * dc); rc.y = packbf(v.z * dc, v.w * dc);
        ((uint2*)ot)[i] = rt;
        ((uint2*)oy)[i] = ry;
        ((uint2*)oc)[i] = rc;
    }
}

// ---------------------------------------------------------------------------
// Merged LGConv gather (bf16 rows, weight=1): one wave per dst node, 8 lanes
// per edge (uint4 = 8 bf16), 2-deep unroll. dot2-bf16 accumulate (no unpack),
// f32 accumulators, 3-round shfl combine. sq: emit dinv^2-scaled output so
// the chained conv can also run at weight=1.
// ---------------------------------------------------------------------------
struct GA {
    const unsigned short* x;
    unsigned short* y;
    const int* csr;
    const int* row;
    const int* cnt;
    const float* dinv;
    int sq;
};

__global__ __launch_bounds__(256) void k_gather3(GA g0, GA g1, GA g2, int perset) {
    const int bset = blockIdx.x / perset;
    const int blk = blockIdx.x - bset * perset;
    const GA ga = (bset == 0) ? g0 : (bset == 1) ? g1 : g2;
    const int node = blk * 4 + (threadIdx.x >> 6);
    const int lane = threadIdx.x & 63;
    const int slot = lane >> 3, fo = lane & 7;
    const int n = ga.cnt[node];
    const unsigned sl = SEL_LO, sh = SEL_HI;
    float acc[8] = {0.f, 0.f, 0.f, 0.f, 0.f, 0.f, 0.f, 0.f};

    if (n > 0) {
        const int* lst = ga.csr + ga.row[node];
        int i = slot;
        for (; i + 8 < n; i += 16) {
            int s0 = lst[i], s1 = lst[i + 8];
            uint4 v0 = *(const uint4*)(ga.x + (size_t)s0 * 64 + fo * 8);
            uint4 v1 = *(const uint4*)(ga.x + (size_t)s1 * 64 + fo * 8);
            dotacc(acc, v0, sl, sh);
            dotacc(acc, v1, sl, sh);
        }
        if (i < n) {
            int s = lst[i];
            uint4 v = *(const uint4*)(ga.x + (size_t)s * 64 + fo * 8);
            dotacc(acc, v, sl, sh);
        }
    }

    #pragma unroll
    for (int off = 8; off < 64; off <<= 1) {
        #pragma unroll
        for (int j = 0; j < 8; ++j) acc[j] += __shfl_xor(acc[j], off);
    }
    if (slot == 0) {
        float dn = ga.dinv[node];
        float sc = ga.sq ? dn * dn : dn;
        uint4 r;
        r.x = packbf(sc * acc[0], sc * acc[1]);
        r.y = packbf(sc * acc[2], sc * acc[3]);
        r.z = packbf(sc * acc[4], sc * acc[5]);
        r.w = packbf(sc * acc[6], sc * acc[7]);
        *(uint4*)(ga.y + (size_t)node * 64 + fo * 8) = r;
    }
}

// ---------------------------------------------------------------------------
// Fused tail, MFMA version, bf16 inputs. 64 nodes/block, 4 waves.
// Phase 1: normalize (8-lane slots) -> bf16 Xn[64][200] LDS + 1/norms.
// Phase 2: H=relu(Xn@W1+b1) via 16x16x32 bf16 MFMA, logits, softmax -> attw.
// Phase 3: out = sum_q attw_q * raw_q (bf16 re-read, f32 out).
// ---------------------------------------------------------------------------
__global__ __launch_bounds__(256) void k_final(const unsigned short* __restrict__ xt,
                                               const unsigned short* __restrict__ xy,
                                               const unsigned short* __restrict__ xc,
                                               const short* __restrict__ W1t,
                                               const float* __restrict__ b1,
                                               const float* __restrict__ W2,
                                               const float* __restrict__ b2,
                                               float* __restrict__ out) {
    __shared__ alignas(16) short Xn[64 * XROW];   // 25600 B
    __shared__ float rnorm[3 * 64];
    __shared__ float attw[64][4];
    const int tid = threadIdx.x;
    const int wid = tid >> 6, lane = tid & 63;
    const int slot = lane >> 3, fo = lane & 7;
    const int m0 = wid * 16;
    const int nbase = blockIdx.x * 64;

    // ---- phase 1: 48 rows per wave (16 nodes x 3 branches), 8-lane slots
    #pragma unroll
    for (int it = 0; it < 6; ++it) {
        int idx = it * 8 + slot;              // 0..47 = branch*16 + noff
        int br = idx >> 4, noff = idx & 15;
        int m = m0 + noff;
        int nodeg = nbase + m;
        const unsigned short* xp = (br == 0) ? xt : (br == 1) ? xy : xc;
        float f[8] = {0.f, 0.f, 0.f, 0.f, 0.f, 0.f, 0.f, 0.f};
        if (nodeg < NN) {
            uint4 v = *(const uint4*)(xp + (size_t)nodeg * 64 + fo * 8);
            f[0] = bflo(v.x); f[1] = bfhi(v.x); f[2] = bflo(v.y); f[3] = bfhi(v.y);
            f[4] = bflo(v.z); f[5] = bfhi(v.z); f[6] = bflo(v.w); f[7] = bfhi(v.w);
        }
        float ss = 0.f;
        #pragma unroll
        for (int j = 0; j < 8; ++j) ss = fmaf(f[j], f[j], ss);
        #pragma unroll
        for (int off = 1; off < 8; off <<= 1) ss += __shfl_xor(ss, off);
        float rn = 1.0f / fmaxf(sqrtf(ss), 1e-12f);
        uint4 r;
        r.x = packbf(f[0] * rn, f[1] * rn);
        r.y = packbf(f[2] * rn, f[3] * rn);
        r.z = packbf(f[4] * rn, f[5] * rn);
        r.w = packbf(f[6] * rn, f[7] * rn);
        *(uint4*)&Xn[m * XROW + br * 64 + fo * 8] = r;
        if (fo == 0) rnorm[br * 64 + m] = rn;
    }
    __syncthreads();

    // ---- phase 2: MFMA GEMM + logits + softmax
    const int mrow = lane & 15, g = lane >> 4;
    bf16x8 afr[6];
    #pragma unroll
    for (int kk = 0; kk < 6; ++kk)
        afr[kk] = *(const bf16x8*)&Xn[(m0 + mrow) * XROW + kk * 32 + g * 8];
    f32x4 acc[8];
    #pragma unroll
    for (int nt = 0; nt < 8; ++nt) acc[nt] = (f32x4){0.f, 0.f, 0.f, 0.f};
    #pragma unroll
    for (int nt = 0; nt < 8; ++nt) {
        const short* wp = W1t + (nt * 16 + mrow) * 192 + g * 8;
        #pragma unroll
        for (int kk = 0; kk < 6; ++kk)
            acc[nt] = __builtin_amdgcn_mfma_f32_16x16x32_bf16(
                afr[kk], *(const bf16x8*)(wp + kk * 32), acc[nt], 0, 0, 0);
    }
    float p[4][3] = {};
    #pragma unroll
    for (int nt = 0; nt < 8; ++nt) {
        int col = nt * 16 + mrow;
        float b1v = b1[col];
        float w20 = W2[col * 3 + 0], w21 = W2[col * 3 + 1], w22 = W2[col * 3 + 2];
        #pragma unroll
        for (int i = 0; i < 4; ++i) {
            float h = fmaxf(acc[nt][i] + b1v, 0.f);
            p[i][0] = fmaf(h, w20, p[i][0]);
            p[i][1] = fmaf(h, w21, p[i][1]);
            p[i][2] = fmaf(h, w22, p[i][2]);
        }
    }
    #pragma unroll
    for (int i = 0; i < 4; ++i)
        #pragma unroll
        for (int off = 8; off > 0; off >>= 1) {
            p[i][0] += __shfl_xor(p[i][0], off);
            p[i][1] += __shfl_xor(p[i][1], off);
            p[i][2] += __shfl_xor(p[i][2], off);
        }
    if (mrow == 0) {
        #pragma unroll
        for (int i = 0; i < 4; ++i) {
            int m = m0 + g * 4 + i;
            float l0 = p[i][0] + b2[0], l1 = p[i][1] + b2[1], l2 = p[i][2] + b2[2];
            float mx = fmaxf(l0, fmaxf(l1, l2));
            float e0 = __expf(l0 - mx), e1 = __expf(l1 - mx), e2 = __expf(l2 - mx);
            float inv = 1.0f / (e0 + e1 + e2);
            attw[m][0] = e0 * inv * rnorm[m];
            attw[m][1] = e1 * inv * rnorm[64 + m];
            attw[m][2] = e2 * inv * rnorm[128 + m];
        }
    }
    __syncthreads();

    // ---- phase 3: weighted sum of raw bf16 rows, f32 coalesced out
    #pragma unroll
    for (int it = 0; it < 2; ++it) {
        int m = m0 + it * 8 + slot;
        int nodeg = nbase + m;
        if (nodeg < NN) {
            size_t base = (size_t)nodeg * 64 + fo * 8;
            uint4 tv = *(const uint4*)(xt + base);
            uint4 yv = *(const uint4*)(xy + base);
            uint4 cv = *(const uint4*)(xc + base);
            float wt = attw[m][0], wy = attw[m][1], wc = attw[m][2];
            float4 lo4, hi4;
            lo4.x = wt * bflo(tv.x) + wy * bflo(yv.x) + wc * bflo(cv.x);
            lo4.y = wt * bfhi(tv.x) + wy * bfhi(yv.x) + wc * bfhi(cv.x);
            lo4.z = wt * bflo(tv.y) + wy * bflo(yv.y) + wc * bflo(cv.y);
            lo4.w = wt * bfhi(tv.y) + wy * bfhi(yv.y) + wc * bfhi(cv.y);
            hi4.x = wt * bflo(tv.z) + wy * bflo(yv.z) + wc * bflo(cv.z);
            hi4.y = wt * bfhi(tv.z) + wy * bfhi(yv.z) + wc * bfhi(cv.z);
            hi4.z = wt * bflo(tv.w) + wy * bflo(yv.w) + wc * bflo(cv.w);
            hi4.w = wt * bfhi(tv.w) + wy * bfhi(yv.w) + wc * bfhi(cv.w);
            *(float4*)(out + base) = lo4;
            *(float4*)(out + base + 4) = hi4;
        }
    }
}

// ---------------------------------------------------------------------------
extern "C" void kernel_launch(void* const* d_in, const int* in_sizes, int n_in,
                              void* d_out, int out_size, void* d_ws, size_t ws_size,
                              hipStream_t stream) {
    const float* init_feat = (const float*)d_in[0];
    const float* W1 = (const float*)d_in[1];
    const float* b1 = (const float*)d_in[2];
    const float* W2 = (const float*)d_in[3];
    const float* b2 = (const float*)d_in[4];
    const int* ei[3] = {(const int*)d_in[5], (const int*)d_in[6], (const int*)d_in[7]}; // title, year, cat

    // workspace: 6 bf16 feature buffers + CSR structures (~100 MB)
    unsigned short* P0t = (unsigned short*)d_ws;        // scaled title init -> later Tfin
    unsigned short* P0y = P0t + (size_t)NN * 64;        // scaled year init  -> later C2
    unsigned short* P0c = P0y + (size_t)NN * 64;        // scaled cat init   -> later Cfin
    unsigned short* T1  = P0c + (size_t)NN * 64;        // title conv1
    unsigned short* C1  = T1 + (size_t)NN * 64;         // cat conv1
    unsigned short* Yfin = C1 + (size_t)NN * 64;        // year final
    float* dinvA = (float*)(Yfin + (size_t)NN * 64);    // [3*N]
    int* cntA = (int*)(dinvA + 3 * NN);                 // [3*N]
    int* rowA = cntA + 3 * NN;                          // [3*N]
    int* gpackedA = rowA + 3 * NN;                      // [3*PADE] (CSR in-place)
    short* W1t = (short*)(gpackedA + (size_t)3 * PADE); // [128*192]
    int* gcurA = (int*)(W1t + 128 * 192);               // [3*NB]

    const int TB = 256;
    const int perset = NN / 4;                          // 25000
    const int finalGrid = (NN + 63) / 64;

    k_prep<<<(128 * 192 + TB - 1) / TB, TB, 0, stream>>>(W1, W1t);
    k_ginit<<<(3 * NB + TB - 1) / TB, TB, 0, stream>>>(gcurA);
    k_bscat<<<3 * NCHUNK, TB, 0, stream>>>(ei[0], ei[1], ei[2], gcurA, gpackedA);
    k_bfin<<<3 * NB, TB, 0, stream>>>(gpackedA, gcurA, cntA, dinvA, rowA);
    k_scale3<<<(NN * 16 + TB - 1) / TB, TB, 0, stream>>>(init_feat, dinvA, P0t, P0y, P0c);

    #define MKGA(xp, yp, s, SQ) \
        GA{ (xp), (yp), gpackedA + (size_t)(s) * PADE, rowA + (s) * NN, \
            cntA + (s) * NN, dinvA + (s) * NN, (SQ) }
    // Round A: cat1 (P0c->C1), title1 (P0t->T1), year (P0y->Yfin)
    {
        GA a0 = MKGA(P0c, C1, 2, 1);
        GA a1 = MKGA(P0t, T1, 0, 1);
        GA a2 = MKGA(P0y, Yfin, 1, 0);
        k_gather3<<<3 * perset, TB, 0, stream>>>(a0, a1, a2, perset);
    }
    // Round B: cat2 (C1 -> P0y as C2), title2 (T1 -> P0t as Tfin)
    {
        GA b0 = MKGA(C1, P0y, 2, 1);
        GA b1g = MKGA(T1, P0t, 0, 0);
        k_gather3<<<2 * perset, TB, 0, stream>>>(b0, b1g, b1g, perset);
    }
    // Round C: cat3 (P0y -> P0c as Cfin)
    {
        GA c0 = MKGA(P0y, P0c, 2, 0);
        k_gather3<<<perset, TB, 0, stream>>>(c0, c0, c0, perset);
    }
    #undef MKGA

    // xt=title(P0t), xy=year(Yfin), xc=cat(P0c)
    k_final<<<finalGrid, TB, 0, stream>>>(P0t, Yfin, P0c, W1t, b1, W2, b2, (float*)d_out);
}